// Round 1
// baseline (561.195 us; speedup 1.0000x reference)
//
#include <hip/hip_runtime.h>
#include <stdint.h>

#define B_       8
#define NPIX     307200        // 480*640
#define SN       1000
#define NBINS    4096
#define MAXCAND  2048
#define NPICK    32            // 8 batches * 4 picks
#define CHUNKS   16
#define CHUNK_EL (NPIX / CHUNKS)   // 19200
#define LCHUNKS  25
#define LROWS    (SN / LCHUNKS)    // 40

// ws layout (bytes)
#define WS_HIST   0                        // 32*4096*4 = 524288
#define WS_NSEL   524288                   // 32*4
#define WS_NCAND  (WS_NSEL + 128)          // 32*4
#define WS_FLAG   (WS_NCAND + 128)         // 4
#define WS_ZERO_SPAN 524800
#define WS_SEL    524800                   // 32*1000*8 = 256000
#define WS_CAND   780800                   // 32*2048*8 = 524288
#define WS_VALS   1305088                  // 32*1000*4 = 128000
#define WS_PART   1433088                  // 200*4

// ---- Threefry-2x32-20, matches jax/_src/prng.py ----
__device__ __forceinline__ void tf2x32(uint32_t k0, uint32_t k1,
                                       uint32_t x0, uint32_t x1,
                                       uint32_t& o0, uint32_t& o1) {
  uint32_t ks2 = k0 ^ k1 ^ 0x1BD11BDAu;
  x0 += k0; x1 += k1;
#define RR(r) { x0 += x1; x1 = (x1 << (r)) | (x1 >> (32 - (r))); x1 ^= x0; }
  RR(13) RR(15) RR(26) RR(6)
  x0 += k1; x1 += ks2 + 1u;
  RR(17) RR(29) RR(16) RR(24)
  x0 += ks2; x1 += k0 + 2u;
  RR(13) RR(15) RR(26) RR(6)
  x0 += k0; x1 += k1 + 3u;
  RR(17) RR(29) RR(16) RR(24)
  x0 += k1; x1 += ks2 + 4u;
  RR(13) RR(15) RR(26) RR(6)
  x0 += ks2; x1 += k0 + 5u;
#undef RR
  o0 = x0; o1 = x1;
}

// partitionable split: key_i = enc(rootkey, (0, i))
__device__ __forceinline__ void pick_key(int pick, uint32_t& k0, uint32_t& k1) {
  tf2x32(0u, 42u, 0u, (uint32_t)pick, k0, k1);
}

// partitionable random_bits (32-bit): enc(key, (hi(p)=0, lo(p)=p)) -> o0 ^ o1
__device__ __forceinline__ uint32_t rbits(uint32_t k0, uint32_t k1, int p) {
  uint32_t o0, o1;
  tf2x32(k0, k1, 0u, (uint32_t)p, o0, o1);
  return o0 ^ o1;
}

__device__ __forceinline__ bool rd_mask(const void* m, long idx, unsigned bytef) {
  if (bytef) return ((const uint8_t*)m)[idx] != 0;
  return ((const int*)m)[idx] != 0;
}

__device__ __forceinline__ bool valid_at(const void* mym, const void* msk,
                                         long base, int p, int t, unsigned bytef) {
  bool my_ = rd_mask(mym, base + p, bytef);
  bool mk_ = rd_mask(msk, base + p, bytef);
  return (t < 2) ? (my_ && mk_) : ((!my_) && mk_);
}

// align-corners bilinear of input (8,1,240,320) at flat out-pixel p of (480,640)
__device__ float bilinear_val(const float* input, int b, int p) {
  int oy = p / 640;
  int ox = p - oy * 640;
  double sy = ((double)oy * 239.0) / 479.0;
  double sx = ((double)ox * 319.0) / 639.0;
  int y0 = (int)sy; if (y0 > 239) y0 = 239;
  int x0 = (int)sx; if (x0 > 319) x0 = 319;
  int y1 = y0 + 1 < 240 ? y0 + 1 : 239;
  int x1 = x0 + 1 < 320 ? x0 + 1 : 319;
  double wy = sy - (double)y0;
  double wx = sx - (double)x0;
  const float* base = input + (size_t)b * 76800;
  double g00 = base[y0 * 320 + x0], g01 = base[y0 * 320 + x1];
  double g10 = base[y1 * 320 + x0], g11 = base[y1 * 320 + x1];
  double v = g00 * (1.0 - wy) * (1.0 - wx) + g01 * (1.0 - wy) * wx
           + g10 * wy * (1.0 - wx) + g11 * wy * wx;
  return (float)v;
}

// byte-packed mask iff some word has only-0/1 bytes with value > 1
__global__ void k_detect(const unsigned* mw, unsigned* flag) {
  __shared__ unsigned s_f;
  if (threadIdx.x == 0) s_f = 0;
  __syncthreads();
  unsigned f = 0;
  for (int i = threadIdx.x; i < 65536; i += 256) {
    unsigned w = mw[i];
    if ((w & 0xFEFEFEFEu) == 0u && w > 1u) f = 1;
  }
  if (f) atomicOr(&s_f, 1u);
  __syncthreads();
  if (threadIdx.x == 0) flag[0] = s_f;
}

__global__ __launch_bounds__(256)
void k_hist(const void* mym, const void* msk, unsigned* ws_u32) {
  int pick = blockIdx.x / CHUNKS;
  int chunk = blockIdx.x % CHUNKS;
  int b = pick >> 2, t = pick & 3;
  unsigned bytef = ws_u32[WS_FLAG / 4];
  uint32_t k0, k1; pick_key(pick, k0, k1);
  unsigned* hist = ws_u32 + pick * NBINS;
  long base = (long)b * NPIX;
  int start = chunk * CHUNK_EL;
  for (int p = start + threadIdx.x; p < start + CHUNK_EL; p += 256) {
    if (valid_at(mym, msk, base, p, t, bytef)) {
      uint32_t m = rbits(k0, k1, p) >> 9;   // uniform monotone in m
      atomicAdd(&hist[m >> 11], 1u);
    }
  }
}

__global__ __launch_bounds__(256)
void k_collect(const void* mym, const void* msk, unsigned* ws_u32,
               uint64_t* sel, uint64_t* cand) {
  __shared__ unsigned s_hist[NBINS];
  __shared__ unsigned s_T;
  int pick = blockIdx.x / CHUNKS;
  int chunk = blockIdx.x % CHUNKS;
  int b = pick >> 2, t = pick & 3;
  unsigned bytef = ws_u32[WS_FLAG / 4];
  const unsigned* hist = ws_u32 + pick * NBINS;
  for (int j = threadIdx.x; j < NBINS; j += 256) s_hist[j] = hist[j];
  __syncthreads();
  if (threadIdx.x == 0) {
    unsigned cum = 0, T = NBINS - 1;
    for (int j = 0; j < NBINS; ++j) {
      unsigned c = s_hist[j];
      if (cum + c >= SN) { T = (unsigned)j; break; }
      cum += c;
    }
    s_T = T;
  }
  __syncthreads();
  unsigned T = s_T;
  uint32_t k0, k1; pick_key(pick, k0, k1);
  unsigned* nsel = ws_u32 + WS_NSEL / 4 + pick;
  unsigned* ncand = ws_u32 + WS_NCAND / 4 + pick;
  uint64_t* selp = sel + (size_t)pick * SN;
  uint64_t* candp = cand + (size_t)pick * MAXCAND;
  long base = (long)b * NPIX;
  int start = chunk * CHUNK_EL;
  for (int p = start + threadIdx.x; p < start + CHUNK_EL; p += 256) {
    if (!valid_at(mym, msk, base, p, t, bytef)) continue;
    uint32_t m = rbits(k0, k1, p) >> 9;
    unsigned bin = m >> 11;
    uint64_t key = ((uint64_t)m << 19) | (uint32_t)p;  // lex (score, index)
    if (bin < T) {
      unsigned s = atomicAdd(nsel, 1u);
      selp[s] = key;
    } else if (bin == T) {
      unsigned s = atomicAdd(ncand, 1u);
      if (s < MAXCAND) candp[s] = key;
    }
  }
}

__global__ __launch_bounds__(1024)
void k_final_sel(const float* input, const float* target,
                 unsigned* ws_u32, uint64_t* sel, uint64_t* cand, float* vals) {
  __shared__ uint64_t s_sel[SN];
  int pick = blockIdx.x;
  int b = pick >> 2, t = pick & 3;
  uint64_t* selp = sel + (size_t)pick * SN;
  uint64_t* candp = cand + (size_t)pick * MAXCAND;
  unsigned nsel = ws_u32[WS_NSEL / 4 + pick];
  unsigned ncand = ws_u32[WS_NCAND / 4 + pick];
  if (ncand > MAXCAND) ncand = MAXCAND;
  int need = SN - (int)nsel;
  if (threadIdx.x == 0) {
    for (int a = 1; a < (int)ncand; ++a) {       // tiny insertion sort (~30-50 elems)
      uint64_t v = candp[a]; int j = a - 1;
      while (j >= 0 && candp[j] > v) { candp[j + 1] = candp[j]; --j; }
      candp[j + 1] = v;
    }
  }
  __syncthreads();
  for (int a = threadIdx.x; a < need; a += blockDim.x) selp[nsel + a] = candp[a];
  __syncthreads();
  for (int a = threadIdx.x; a < SN; a += blockDim.x) s_sel[a] = selp[a];
  __syncthreads();
  // rank = position in ascending (score,index) order == top_k output order
  for (int a = threadIdx.x; a < SN; a += blockDim.x) {
    uint64_t key = s_sel[a];
    int rank = 0;
    for (int j = 0; j < SN; ++j) rank += (s_sel[j] < key) ? 1 : 0;
    int p = (int)(key & 0x7FFFFULL);
    float v = (t & 1) ? target[(long)b * NPIX + p] : bilinear_val(input, b, p);
    vals[(size_t)pick * SN + rank] = v;
  }
}

__global__ __launch_bounds__(256)
void k_loss(const float* vals, float* partials) {
  int bb = blockIdx.x / LCHUNKS;
  int ch = blockIdx.x % LCHUNKS;
  const float* ii = vals + (size_t)(4 * bb + 0) * SN;
  const float* it = vals + (size_t)(4 * bb + 1) * SN;
  const float* oi = vals + (size_t)(4 * bb + 2) * SN;
  const float* ot = vals + (size_t)(4 * bb + 3) * SN;
  __shared__ float s_oi[SN], s_ot[SN];
  for (int j = threadIdx.x; j < SN; j += 256) { s_oi[j] = oi[j]; s_ot[j] = ot[j]; }
  __syncthreads();
  float acc = 0.f;
  int a0 = ch * LROWS, a1 = a0 + LROWS;
  for (int a = a0; a < a1; ++a) {
    float iia = ii[a], ita = it[a];
    for (int j = threadIdx.x; j < SN; j += 256) {
      acc += fabsf(fabsf(iia - s_oi[j]) - fabsf(ita - s_ot[j]));
    }
  }
  __shared__ float s_red[256];
  s_red[threadIdx.x] = acc;
  __syncthreads();
  for (int s = 128; s > 0; s >>= 1) {
    if ((int)threadIdx.x < s) s_red[threadIdx.x] += s_red[threadIdx.x + s];
    __syncthreads();
  }
  if (threadIdx.x == 0) partials[blockIdx.x] = s_red[0];
}

__global__ void k_sum(const float* partials, float* out) {
  if (threadIdx.x == 0 && blockIdx.x == 0) {
    double tot = 0.0;
    for (int bb = 0; bb < B_; ++bb) {
      double s = 0.0;
      for (int c = 0; c < LCHUNKS; ++c) s += (double)partials[bb * LCHUNKS + c];
      tot += s * 1e-6;
    }
    out[0] = (float)tot;
  }
}

extern "C" void kernel_launch(void* const* d_in, const int* in_sizes, int n_in,
                              void* d_out, int out_size, void* d_ws, size_t ws_size,
                              hipStream_t stream) {
  const float* input  = (const float*)d_in[0];
  const float* target = (const float*)d_in[1];
  const void* mym = d_in[2];
  const void* msk = d_in[3];
  (void)in_sizes; (void)n_in; (void)out_size; (void)ws_size;

  unsigned* ws_u32 = (unsigned*)d_ws;
  uint64_t* sel   = (uint64_t*)((char*)d_ws + WS_SEL);
  uint64_t* cand  = (uint64_t*)((char*)d_ws + WS_CAND);
  float* vals     = (float*)((char*)d_ws + WS_VALS);
  float* partials = (float*)((char*)d_ws + WS_PART);
  unsigned* flag  = ws_u32 + WS_FLAG / 4;

  hipMemsetAsync(d_ws, 0, WS_ZERO_SPAN, stream);                 // hist + counters
  k_detect<<<1, 256, 0, stream>>>((const unsigned*)mym, flag);
  k_hist<<<NPICK * CHUNKS, 256, 0, stream>>>(mym, msk, ws_u32);
  k_collect<<<NPICK * CHUNKS, 256, 0, stream>>>(mym, msk, ws_u32, sel, cand);
  k_final_sel<<<NPICK, 1024, 0, stream>>>(input, target, ws_u32, sel, cand, vals);
  k_loss<<<B_ * LCHUNKS, 256, 0, stream>>>(vals, partials);
  k_sum<<<1, 64, 0, stream>>>(partials, (float*)d_out);
}

// Round 2
// 467.258 us; speedup vs baseline: 1.2010x; 1.2010x over previous
//
#include <hip/hip_runtime.h>
#include <stdint.h>

#define B_       8
#define NPIX     307200        // 480*640
#define SN       1000
#define NPICK    32            // 8 batches * 4 picks
#define T0BITS   17
#define T0       (1u << T0BITS)     // candidate filter: m < 2^17 (1/64 of valid)
#define MAXCAND  8192
#define FBINS    1024
#define FSHIFT   (T0BITS - 10)      // bin = m >> 7
#define CHUNKS   120
#define CHUNK_PX (NPIX / CHUNKS)    // 2560
#define LCHUNKS  25
#define LROWS    (SN / LCHUNKS)     // 40

// ws layout (bytes)
#define WS_NCAND 0                         // 32*4 = 128
#define WS_FLAG  128                       // 4
#define WS_KEYS  192                       // 32*2*4 = 256
#define WS_ZERO  192                       // memset span (ncand + flag)
#define WS_CAND  512                       // 32*8192*8 = 2097152
#define WS_VALS  (512 + 2097152)           // 32*1000*4 = 128000
#define WS_PART  (WS_VALS + 128000)        // 200*4

// ---- Threefry-2x32-20, matches jax/_src/prng.py ----
__device__ __forceinline__ void tf2x32(uint32_t k0, uint32_t k1,
                                       uint32_t x0, uint32_t x1,
                                       uint32_t& o0, uint32_t& o1) {
  uint32_t ks2 = k0 ^ k1 ^ 0x1BD11BDAu;
  x0 += k0; x1 += k1;
#define RR(r) { x0 += x1; x1 = (x1 << (r)) | (x1 >> (32 - (r))); x1 ^= x0; }
  RR(13) RR(15) RR(26) RR(6)
  x0 += k1; x1 += ks2 + 1u;
  RR(17) RR(29) RR(16) RR(24)
  x0 += ks2; x1 += k0 + 2u;
  RR(13) RR(15) RR(26) RR(6)
  x0 += k0; x1 += k1 + 3u;
  RR(17) RR(29) RR(16) RR(24)
  x0 += k1; x1 += ks2 + 4u;
  RR(13) RR(15) RR(26) RR(6)
  x0 += ks2; x1 += k0 + 5u;
#undef RR
  o0 = x0; o1 = x1;
}

__device__ __forceinline__ void pick_key(int pick, uint32_t& k0, uint32_t& k1) {
  tf2x32(0u, 42u, 0u, (uint32_t)pick, k0, k1);
}

__device__ __forceinline__ uint32_t rbits(uint32_t k0, uint32_t k1, int p) {
  uint32_t o0, o1;
  tf2x32(k0, k1, 0u, (uint32_t)p, o0, o1);
  return o0 ^ o1;
}

// align-corners bilinear of input (8,1,240,320) at flat out-pixel p of (480,640)
__device__ float bilinear_val(const float* input, int b, int p) {
  int oy = p / 640;
  int ox = p - oy * 640;
  double sy = ((double)oy * 239.0) / 479.0;
  double sx = ((double)ox * 319.0) / 639.0;
  int y0 = (int)sy; if (y0 > 239) y0 = 239;
  int x0 = (int)sx; if (x0 > 319) x0 = 319;
  int y1 = y0 + 1 < 240 ? y0 + 1 : 239;
  int x1 = x0 + 1 < 320 ? x0 + 1 : 319;
  double wy = sy - (double)y0;
  double wx = sx - (double)x0;
  const float* base = input + (size_t)b * 76800;
  double g00 = base[y0 * 320 + x0], g01 = base[y0 * 320 + x1];
  double g10 = base[y1 * 320 + x0], g11 = base[y1 * 320 + x1];
  double v = g00 * (1.0 - wy) * (1.0 - wx) + g01 * (1.0 - wy) * wx
           + g10 * wy * (1.0 - wx) + g11 * wy * wx;
  return (float)v;
}

// byte-packed mask detection + precompute all 32 pick keys
__global__ void k_detect(const unsigned* mw, unsigned* ws_u32) {
  __shared__ unsigned s_f;
  if (threadIdx.x == 0) s_f = 0;
  __syncthreads();
  unsigned f = 0;
  for (int i = threadIdx.x; i < 16384; i += 256) {
    unsigned w = mw[i];
    if ((w & 0xFEFEFEFEu) == 0u && w > 1u) f = 1;   // only possible if byte-packed bools
  }
  if (f) atomicOr(&s_f, 1u);
  __syncthreads();
  if (threadIdx.x == 0) ws_u32[WS_FLAG / 4] = s_f;
  if (threadIdx.x < NPICK) {
    uint32_t k0, k1; pick_key(threadIdx.x, k0, k1);
    ws_u32[WS_KEYS / 4 + threadIdx.x * 2]     = k0;
    ws_u32[WS_KEYS / 4 + threadIdx.x * 2 + 1] = k1;
  }
}

// single fused scan: read masks once, 2 threefry per valid pixel, emit m < T0
__global__ __launch_bounds__(256)
void k_cand(const void* mym, const void* msk, unsigned* ws_u32, uint64_t* cand) {
  int b = blockIdx.x / CHUNKS;
  int chunk = blockIdx.x % CHUNKS;
  unsigned bytef = ws_u32[WS_FLAG / 4];
  const unsigned* keys = ws_u32 + WS_KEYS / 4;
  uint32_t k00 = keys[(b * 4 + 0) * 2], k01 = keys[(b * 4 + 0) * 2 + 1];
  uint32_t k10 = keys[(b * 4 + 1) * 2], k11 = keys[(b * 4 + 1) * 2 + 1];
  uint32_t k20 = keys[(b * 4 + 2) * 2], k21 = keys[(b * 4 + 2) * 2 + 1];
  uint32_t k30 = keys[(b * 4 + 3) * 2], k31 = keys[(b * 4 + 3) * 2 + 1];
  unsigned* ncand = ws_u32 + WS_NCAND / 4;
  long base = (long)b * NPIX;
  int start = chunk * CHUNK_PX;
  for (int p = start + threadIdx.x; p < start + CHUNK_PX; p += 256) {
    bool my_, mk_;
    if (bytef) {
      my_ = ((const uint8_t*)mym)[base + p] != 0;
      mk_ = ((const uint8_t*)msk)[base + p] != 0;
    } else {
      my_ = ((const int*)mym)[base + p] != 0;
      mk_ = ((const int*)msk)[base + p] != 0;
    }
    if (!mk_) continue;
    // inside pixels feed picks {0,1}, outside feed picks {2,3} (per-lane select)
    uint32_t ka0 = my_ ? k00 : k20, ka1 = my_ ? k01 : k21;
    uint32_t kb0 = my_ ? k10 : k30, kb1 = my_ ? k11 : k31;
    int pickA = b * 4 + (my_ ? 0 : 2);
    uint32_t mA = rbits(ka0, ka1, p) >> 9;
    if (mA < T0) {
      unsigned s = atomicAdd(&ncand[pickA], 1u);
      if (s < MAXCAND) cand[(size_t)pickA * MAXCAND + s] = ((uint64_t)mA << 19) | (uint32_t)p;
    }
    uint32_t mB = rbits(kb0, kb1, p) >> 9;
    if (mB < T0) {
      unsigned s = atomicAdd(&ncand[pickA + 1], 1u);
      if (s < MAXCAND) cand[(size_t)(pickA + 1) * MAXCAND + s] = ((uint64_t)mB << 19) | (uint32_t)p;
    }
  }
}

// per pick: LDS histogram -> threshold -> exact boundary -> rank -> gather values
__global__ __launch_bounds__(1024)
void k_fsel(const float* input, const float* target, unsigned* ws_u32,
            const uint64_t* cand, float* vals) {
  __shared__ unsigned s_hist[FBINS];
  __shared__ uint64_t s_sel[SN];
  __shared__ uint64_t s_bnd[128];
  __shared__ unsigned s_cnt, s_bcnt, s_T, s_nb;
  int pick = blockIdx.x;
  int b = pick >> 2, t = pick & 3;
  unsigned nc = ws_u32[WS_NCAND / 4 + pick];
  if (nc > MAXCAND) nc = MAXCAND;
  const uint64_t* cp = cand + (size_t)pick * MAXCAND;
  for (int j = threadIdx.x; j < FBINS; j += 1024) s_hist[j] = 0;
  if (threadIdx.x == 0) { s_cnt = 0; s_bcnt = 0; }
  __syncthreads();
  for (int i = threadIdx.x; i < (int)nc; i += 1024) {
    unsigned m = (unsigned)(cp[i] >> 19);
    atomicAdd(&s_hist[m >> FSHIFT], 1u);
  }
  __syncthreads();
  if (threadIdx.x == 0) {
    unsigned cum = 0, T = FBINS - 1, nb = 0;
    for (int j = 0; j < FBINS; ++j) {
      unsigned c = s_hist[j];
      if (cum + c >= SN) { T = (unsigned)j; nb = cum; break; }
      cum += c;
    }
    s_T = T; s_nb = nb;
  }
  __syncthreads();
  unsigned T = s_T, nb = s_nb;
  for (int i = threadIdx.x; i < (int)nc; i += 1024) {
    uint64_t k = cp[i];
    unsigned bin = ((unsigned)(k >> 19)) >> FSHIFT;
    if (bin < T) {
      unsigned s = atomicAdd(&s_cnt, 1u);
      s_sel[s] = k;
    } else if (bin == T) {
      unsigned s = atomicAdd(&s_bcnt, 1u);
      if (s < 128) s_bnd[s] = k;
    }
  }
  __syncthreads();
  if (threadIdx.x == 0) {
    int bc = (int)s_bcnt; if (bc > 128) bc = 128;
    for (int a = 1; a < bc; ++a) {             // tiny insertion sort (~5-30 elems)
      uint64_t v = s_bnd[a]; int j = a - 1;
      while (j >= 0 && s_bnd[j] > v) { s_bnd[j + 1] = s_bnd[j]; --j; }
      s_bnd[j + 1] = v;
    }
    int need = SN - (int)nb;
    for (int a = 0; a < need; ++a) s_sel[nb + a] = s_bnd[a];
  }
  __syncthreads();
  // rank = position in ascending (score,index) order == top_k output order
  for (int a = threadIdx.x; a < SN; a += 1024) {
    uint64_t key = s_sel[a];
    int rank = 0;
    for (int j = 0; j < SN; ++j) rank += (s_sel[j] < key) ? 1 : 0;
    int p = (int)(key & 0x7FFFFULL);
    float v = (t & 1) ? target[(long)b * NPIX + p] : bilinear_val(input, b, p);
    vals[(size_t)pick * SN + rank] = v;
  }
}

__global__ __launch_bounds__(256)
void k_loss(const float* vals, float* partials) {
  int bb = blockIdx.x / LCHUNKS;
  int ch = blockIdx.x % LCHUNKS;
  const float* ii = vals + (size_t)(4 * bb + 0) * SN;
  const float* it = vals + (size_t)(4 * bb + 1) * SN;
  const float* oi = vals + (size_t)(4 * bb + 2) * SN;
  const float* ot = vals + (size_t)(4 * bb + 3) * SN;
  __shared__ float s_oi[SN], s_ot[SN];
  for (int j = threadIdx.x; j < SN; j += 256) { s_oi[j] = oi[j]; s_ot[j] = ot[j]; }
  __syncthreads();
  float acc = 0.f;
  int a0 = ch * LROWS, a1 = a0 + LROWS;
  for (int a = a0; a < a1; ++a) {
    float iia = ii[a], ita = it[a];
    for (int j = threadIdx.x; j < SN; j += 256) {
      acc += fabsf(fabsf(iia - s_oi[j]) - fabsf(ita - s_ot[j]));
    }
  }
  __shared__ float s_red[256];
  s_red[threadIdx.x] = acc;
  __syncthreads();
  for (int s = 128; s > 0; s >>= 1) {
    if ((int)threadIdx.x < s) s_red[threadIdx.x] += s_red[threadIdx.x + s];
    __syncthreads();
  }
  if (threadIdx.x == 0) partials[blockIdx.x] = s_red[0];
}

__global__ void k_sum(const float* partials, float* out) {
  if (threadIdx.x == 0 && blockIdx.x == 0) {
    double tot = 0.0;
    for (int bb = 0; bb < B_; ++bb) {
      double s = 0.0;
      for (int c = 0; c < LCHUNKS; ++c) s += (double)partials[bb * LCHUNKS + c];
      tot += s * 1e-6;
    }
    out[0] = (float)tot;
  }
}

extern "C" void kernel_launch(void* const* d_in, const int* in_sizes, int n_in,
                              void* d_out, int out_size, void* d_ws, size_t ws_size,
                              hipStream_t stream) {
  const float* input  = (const float*)d_in[0];
  const float* target = (const float*)d_in[1];
  const void* mym = d_in[2];
  const void* msk = d_in[3];
  (void)in_sizes; (void)n_in; (void)out_size; (void)ws_size;

  unsigned* ws_u32 = (unsigned*)d_ws;
  uint64_t* cand  = (uint64_t*)((char*)d_ws + WS_CAND);
  float* vals     = (float*)((char*)d_ws + WS_VALS);
  float* partials = (float*)((char*)d_ws + WS_PART);

  hipMemsetAsync(d_ws, 0, WS_ZERO, stream);                 // ncand + flag
  k_detect<<<1, 256, 0, stream>>>((const unsigned*)mym, ws_u32);
  k_cand<<<B_ * CHUNKS, 256, 0, stream>>>(mym, msk, ws_u32, cand);
  k_fsel<<<NPICK, 1024, 0, stream>>>(input, target, ws_u32, cand, vals);
  k_loss<<<B_ * LCHUNKS, 256, 0, stream>>>(vals, partials);
  k_sum<<<1, 64, 0, stream>>>(partials, (float*)d_out);
}

// Round 3
// 82.554 us; speedup vs baseline: 6.7979x; 5.6600x over previous
//
#include <hip/hip_runtime.h>
#include <stdint.h>

#define B_       8
#define NPIX     307200        // 480*640
#define SN       1000
#define NPICK    32            // 8 batches * 4 picks
#define T0BITS   17
#define T0       (1u << T0BITS)     // candidate filter: m < 2^17 (~1/64 of valid)
#define MAXCAND  8192
#define FBINS    1024
#define FSHIFT   (T0BITS - 10)      // bin = m >> 7
#define CHUNKS   150
#define CHUNK_PX (NPIX / CHUNKS)    // 2048
#define CAP      256                // per-block per-pick LDS candidate capacity
#define LCHUNKS  25
#define LROWS    (SN / LCHUNKS)     // 40

// ws layout (bytes)
#define WS_NCAND 0                         // 32*4 = 128
#define WS_FLAG  128                       // 4
#define WS_KEYS  192                       // 32*2*4 = 256
#define WS_ZERO  192                       // memset span (ncand + flag)
#define WS_CAND  512                       // 32*8192*8 = 2097152
#define WS_VALS  (512 + 2097152)           // 32*1000*4 = 128000
#define WS_PART  (WS_VALS + 128000)        // 200*4

// ---- Threefry-2x32-20, matches jax/_src/prng.py ----
__device__ __forceinline__ void tf2x32(uint32_t k0, uint32_t k1,
                                       uint32_t x0, uint32_t x1,
                                       uint32_t& o0, uint32_t& o1) {
  uint32_t ks2 = k0 ^ k1 ^ 0x1BD11BDAu;
  x0 += k0; x1 += k1;
#define RR(r) { x0 += x1; x1 = (x1 << (r)) | (x1 >> (32 - (r))); x1 ^= x0; }
  RR(13) RR(15) RR(26) RR(6)
  x0 += k1; x1 += ks2 + 1u;
  RR(17) RR(29) RR(16) RR(24)
  x0 += ks2; x1 += k0 + 2u;
  RR(13) RR(15) RR(26) RR(6)
  x0 += k0; x1 += k1 + 3u;
  RR(17) RR(29) RR(16) RR(24)
  x0 += k1; x1 += ks2 + 4u;
  RR(13) RR(15) RR(26) RR(6)
  x0 += ks2; x1 += k0 + 5u;
#undef RR
  o0 = x0; o1 = x1;
}

__device__ __forceinline__ void pick_key(int pick, uint32_t& k0, uint32_t& k1) {
  tf2x32(0u, 42u, 0u, (uint32_t)pick, k0, k1);
}

__device__ __forceinline__ uint32_t rbits(uint32_t k0, uint32_t k1, int p) {
  uint32_t o0, o1;
  tf2x32(k0, k1, 0u, (uint32_t)p, o0, o1);
  return o0 ^ o1;
}

// align-corners bilinear of input (8,1,240,320) at flat out-pixel p of (480,640)
__device__ float bilinear_val(const float* input, int b, int p) {
  int oy = p / 640;
  int ox = p - oy * 640;
  double sy = ((double)oy * 239.0) / 479.0;
  double sx = ((double)ox * 319.0) / 639.0;
  int y0 = (int)sy; if (y0 > 239) y0 = 239;
  int x0 = (int)sx; if (x0 > 319) x0 = 319;
  int y1 = y0 + 1 < 240 ? y0 + 1 : 239;
  int x1 = x0 + 1 < 320 ? x0 + 1 : 319;
  double wy = sy - (double)y0;
  double wx = sx - (double)x0;
  const float* base = input + (size_t)b * 76800;
  double g00 = base[y0 * 320 + x0], g01 = base[y0 * 320 + x1];
  double g10 = base[y1 * 320 + x0], g11 = base[y1 * 320 + x1];
  double v = g00 * (1.0 - wy) * (1.0 - wx) + g01 * (1.0 - wy) * wx
           + g10 * wy * (1.0 - wx) + g11 * wy * wx;
  return (float)v;
}

// byte-packed mask detection + precompute all 32 pick keys
__global__ void k_detect(const unsigned* mw, unsigned* ws_u32) {
  __shared__ unsigned s_f;
  if (threadIdx.x == 0) s_f = 0;
  __syncthreads();
  unsigned f = 0;
  for (int i = threadIdx.x; i < 16384; i += 256) {
    unsigned w = mw[i];
    if ((w & 0xFEFEFEFEu) == 0u && w > 1u) f = 1;   // only possible if byte-packed bools
  }
  if (f) atomicOr(&s_f, 1u);
  __syncthreads();
  if (threadIdx.x == 0) ws_u32[WS_FLAG / 4] = s_f;
  if (threadIdx.x < NPICK) {
    uint32_t k0, k1; pick_key(threadIdx.x, k0, k1);
    ws_u32[WS_KEYS / 4 + threadIdx.x * 2]     = k0;
    ws_u32[WS_KEYS / 4 + threadIdx.x * 2 + 1] = k1;
  }
}

// fused scan: read masks once, 2 threefry per valid pixel, buffer candidates in
// LDS, ONE global atomic per (block,pick) to reserve output space.
__global__ __launch_bounds__(256)
void k_cand(const void* mym, const void* msk, unsigned* ws_u32, uint64_t* cand) {
  __shared__ uint64_t s_cand[4][CAP];
  __shared__ unsigned s_cnt[4];
  __shared__ unsigned s_base[4];
  int b = blockIdx.x / CHUNKS;
  int chunk = blockIdx.x % CHUNKS;
  int tid = threadIdx.x;
  if (tid < 4) s_cnt[tid] = 0;
  __syncthreads();
  unsigned bytef = ws_u32[WS_FLAG / 4];
  const unsigned* keys = ws_u32 + WS_KEYS / 4;
  uint32_t kk[4][2];
  for (int t = 0; t < 4; ++t) {
    kk[t][0] = keys[(b * 4 + t) * 2];
    kk[t][1] = keys[(b * 4 + t) * 2 + 1];
  }
  long base = (long)b * NPIX;
  int start = chunk * CHUNK_PX;

#define EMIT(my_, p) do {                                                     \
    int t0_ = (my_) ? 0 : 2;                                                  \
    uint32_t mA_ = rbits(kk[t0_][0], kk[t0_][1], (p)) >> 9;                   \
    if (mA_ < T0) {                                                           \
      unsigned s_ = atomicAdd(&s_cnt[t0_], 1u);                               \
      if (s_ < CAP) s_cand[t0_][s_] = ((uint64_t)mA_ << 19) | (uint32_t)(p);  \
    }                                                                         \
    uint32_t mB_ = rbits(kk[t0_ + 1][0], kk[t0_ + 1][1], (p)) >> 9;           \
    if (mB_ < T0) {                                                           \
      unsigned s_ = atomicAdd(&s_cnt[t0_ + 1], 1u);                           \
      if (s_ < CAP) s_cand[t0_ + 1][s_] = ((uint64_t)mB_ << 19) | (uint32_t)(p); \
    }                                                                         \
  } while (0)

  if (bytef) {
    const unsigned* myw = (const unsigned*)((const uint8_t*)mym + base + start);
    const unsigned* mkw = (const unsigned*)((const uint8_t*)msk + base + start);
    for (int it = 0; it < CHUNK_PX / 1024; ++it) {
      int wi = it * 256 + tid;
      unsigned wk = mkw[wi];
      if (wk == 0) continue;
      unsigned wm = myw[wi];
      int p0 = start + wi * 4;
      for (int s = 0; s < 4; ++s) {
        if (((wk >> (8 * s)) & 0xFFu) == 0u) continue;
        bool my_ = ((wm >> (8 * s)) & 0xFFu) != 0u;
        EMIT(my_, p0 + s);
      }
    }
  } else {
    const int* my4 = (const int*)mym;
    const int* mk4 = (const int*)msk;
    for (int p = start + tid; p < start + CHUNK_PX; p += 256) {
      if (mk4[base + p] == 0) continue;
      bool my_ = my4[base + p] != 0;
      EMIT(my_, p);
    }
  }
#undef EMIT
  __syncthreads();
  if (tid < 4) {
    unsigned c = s_cnt[tid]; if (c > CAP) c = CAP;
    s_cnt[tid] = c;
    s_base[tid] = atomicAdd(&ws_u32[WS_NCAND / 4 + b * 4 + tid], c);
  }
  __syncthreads();
  for (int pk = 0; pk < 4; ++pk) {
    unsigned c = s_cnt[pk], bs = s_base[pk];
    uint64_t* outp = cand + (size_t)(b * 4 + pk) * MAXCAND;
    for (unsigned i = tid; i < c; i += 256) {
      unsigned d = bs + i;
      if (d < MAXCAND) outp[d] = s_cand[pk][i];
    }
  }
}

// per pick: LDS histogram -> parallel prefix scan -> collect <=1024 survivors
// -> bitonic sort -> gather values in rank order
__global__ __launch_bounds__(1024)
void k_fsel(const float* input, const float* target, unsigned* ws_u32,
            const uint64_t* cand, float* vals) {
  __shared__ unsigned s_hist[FBINS];     // becomes inclusive cumsum
  __shared__ uint64_t s_sel[1024];
  __shared__ unsigned s_cnt, s_T;
  int tid = threadIdx.x;
  int pick = blockIdx.x;
  int b = pick >> 2, t = pick & 3;
  unsigned nc = ws_u32[WS_NCAND / 4 + pick];
  if (nc > MAXCAND) nc = MAXCAND;
  const uint64_t* cp = cand + (size_t)pick * MAXCAND;
  s_hist[tid] = 0;
  if (tid == 0) s_cnt = 0;
  __syncthreads();
  for (int i = tid; i < (int)nc; i += 1024) {
    unsigned m = (unsigned)(cp[i] >> 19);
    atomicAdd(&s_hist[m >> FSHIFT], 1u);
  }
  __syncthreads();
  // Hillis-Steele inclusive scan over 1024 bins
  for (int off = 1; off < FBINS; off <<= 1) {
    unsigned add = (tid >= off) ? s_hist[tid - off] : 0u;
    __syncthreads();
    s_hist[tid] += add;
    __syncthreads();
  }
  // threshold bin: first T with cum[T] >= SN
  if (s_hist[tid] >= SN && (tid == 0 || s_hist[tid - 1] < SN)) s_T = (unsigned)tid;
  __syncthreads();
  unsigned T = s_T;
  // collect all keys with bin <= T (count = cum[T], ~SN + few); order arbitrary
  for (int i = tid; i < (int)nc; i += 1024) {
    uint64_t k = cp[i];
    unsigned bin = ((unsigned)(k >> 19)) >> FSHIFT;
    if (bin <= T) {
      unsigned s = atomicAdd(&s_cnt, 1u);
      if (s < 1024) s_sel[s] = k;
    }
  }
  __syncthreads();
  unsigned cnt = s_cnt; if (cnt > 1024) cnt = 1024;
  if (tid >= (int)cnt) s_sel[tid] = ~0ULL;     // pad
  __syncthreads();
  // bitonic sort, ascending; keys unique -> sorted position == top_k rank
  for (int k = 2; k <= 1024; k <<= 1) {
    for (int j = k >> 1; j > 0; j >>= 1) {
      int ixj = tid ^ j;
      if (ixj > tid) {
        uint64_t a = s_sel[tid], bb = s_sel[ixj];
        bool up = ((tid & k) == 0);
        if ((a > bb) == up) { s_sel[tid] = bb; s_sel[ixj] = a; }
      }
      __syncthreads();
    }
  }
  if (tid < SN) {
    uint64_t key = s_sel[tid];
    int p = (int)(key & 0x7FFFFULL);
    float v = (t & 1) ? target[(long)b * NPIX + p] : bilinear_val(input, b, p);
    vals[(size_t)pick * SN + tid] = v;
  }
}

__global__ __launch_bounds__(256)
void k_loss(const float* vals, float* partials) {
  int bb = blockIdx.x / LCHUNKS;
  int ch = blockIdx.x % LCHUNKS;
  const float* ii = vals + (size_t)(4 * bb + 0) * SN;
  const float* it = vals + (size_t)(4 * bb + 1) * SN;
  const float* oi = vals + (size_t)(4 * bb + 2) * SN;
  const float* ot = vals + (size_t)(4 * bb + 3) * SN;
  __shared__ float s_oi[SN], s_ot[SN];
  for (int j = threadIdx.x; j < SN; j += 256) { s_oi[j] = oi[j]; s_ot[j] = ot[j]; }
  __syncthreads();
  float acc = 0.f;
  int a0 = ch * LROWS, a1 = a0 + LROWS;
  for (int a = a0; a < a1; ++a) {
    float iia = ii[a], ita = it[a];
    for (int j = threadIdx.x; j < SN; j += 256) {
      acc += fabsf(fabsf(iia - s_oi[j]) - fabsf(ita - s_ot[j]));
    }
  }
  __shared__ float s_red[256];
  s_red[threadIdx.x] = acc;
  __syncthreads();
  for (int s = 128; s > 0; s >>= 1) {
    if ((int)threadIdx.x < s) s_red[threadIdx.x] += s_red[threadIdx.x + s];
    __syncthreads();
  }
  if (threadIdx.x == 0) partials[blockIdx.x] = s_red[0];
}

__global__ void k_sum(const float* partials, float* out) {
  if (threadIdx.x == 0 && blockIdx.x == 0) {
    double tot = 0.0;
    for (int bb = 0; bb < B_; ++bb) {
      double s = 0.0;
      for (int c = 0; c < LCHUNKS; ++c) s += (double)partials[bb * LCHUNKS + c];
      tot += s * 1e-6;
    }
    out[0] = (float)tot;
  }
}

extern "C" void kernel_launch(void* const* d_in, const int* in_sizes, int n_in,
                              void* d_out, int out_size, void* d_ws, size_t ws_size,
                              hipStream_t stream) {
  const float* input  = (const float*)d_in[0];
  const float* target = (const float*)d_in[1];
  const void* mym = d_in[2];
  const void* msk = d_in[3];
  (void)in_sizes; (void)n_in; (void)out_size; (void)ws_size;

  unsigned* ws_u32 = (unsigned*)d_ws;
  uint64_t* cand  = (uint64_t*)((char*)d_ws + WS_CAND);
  float* vals     = (float*)((char*)d_ws + WS_VALS);
  float* partials = (float*)((char*)d_ws + WS_PART);

  hipMemsetAsync(d_ws, 0, WS_ZERO, stream);                 // ncand + flag
  k_detect<<<1, 256, 0, stream>>>((const unsigned*)mym, ws_u32);
  k_cand<<<B_ * CHUNKS, 256, 0, stream>>>(mym, msk, ws_u32, cand);
  k_fsel<<<NPICK, 1024, 0, stream>>>(input, target, ws_u32, cand, vals);
  k_loss<<<B_ * LCHUNKS, 256, 0, stream>>>(vals, partials);
  k_sum<<<1, 64, 0, stream>>>(partials, (float*)d_out);
}

// Round 4
// 78.797 us; speedup vs baseline: 7.1221x; 1.0477x over previous
//
#include <hip/hip_runtime.h>
#include <stdint.h>

#define B_       8
#define NPIX     307200        // 480*640
#define SN       1000
#define NPICK    32            // 8 batches * 4 picks
#define T0BITS   17
#define T0       (1u << T0BITS)     // candidate filter: m < 2^17 (~1/64 of valid)
#define MAXCAND  8192
#define FBINS    1024
#define FSHIFT   (T0BITS - 10)      // bin = m >> 7
#define CHUNKS   150
#define CHUNK_PX (NPIX / CHUNKS)    // 2048
#define CAP      256                // per-block per-pick LDS candidate capacity
#define LCHUNKS  25
#define LROWS    (SN / LCHUNKS)     // 40
#define NLOSS    (B_ * LCHUNKS)     // 200

// ws layout (bytes)
#define WS_NCAND 0                         // 32*4 = 128
#define WS_FLAG  128                       // 4
#define WS_DONE  132                       // 4
#define WS_KEYS  192                       // 32*2*4 = 256
#define WS_CAND  512                       // 32*8192*8 = 2097152
#define WS_VALS  (512 + 2097152)           // 32*1000*4 = 128000
#define WS_PART  (WS_VALS + 128000)        // 200*4

// ---- Threefry-2x32-20, matches jax/_src/prng.py ----
__device__ __forceinline__ void tf2x32(uint32_t k0, uint32_t k1,
                                       uint32_t x0, uint32_t x1,
                                       uint32_t& o0, uint32_t& o1) {
  uint32_t ks2 = k0 ^ k1 ^ 0x1BD11BDAu;
  x0 += k0; x1 += k1;
#define RR(r) { x0 += x1; x1 = (x1 << (r)) | (x1 >> (32 - (r))); x1 ^= x0; }
  RR(13) RR(15) RR(26) RR(6)
  x0 += k1; x1 += ks2 + 1u;
  RR(17) RR(29) RR(16) RR(24)
  x0 += ks2; x1 += k0 + 2u;
  RR(13) RR(15) RR(26) RR(6)
  x0 += k0; x1 += k1 + 3u;
  RR(17) RR(29) RR(16) RR(24)
  x0 += k1; x1 += ks2 + 4u;
  RR(13) RR(15) RR(26) RR(6)
  x0 += ks2; x1 += k0 + 5u;
#undef RR
  o0 = x0; o1 = x1;
}

__device__ __forceinline__ void pick_key(int pick, uint32_t& k0, uint32_t& k1) {
  tf2x32(0u, 42u, 0u, (uint32_t)pick, k0, k1);
}

__device__ __forceinline__ uint32_t rbits(uint32_t k0, uint32_t k1, int p) {
  uint32_t o0, o1;
  tf2x32(k0, k1, 0u, (uint32_t)p, o0, o1);
  return o0 ^ o1;
}

// align-corners bilinear of input (8,1,240,320) at flat out-pixel p of (480,640)
__device__ float bilinear_val(const float* input, int b, int p) {
  int oy = p / 640;
  int ox = p - oy * 640;
  double sy = ((double)oy * 239.0) / 479.0;
  double sx = ((double)ox * 319.0) / 639.0;
  int y0 = (int)sy; if (y0 > 239) y0 = 239;
  int x0 = (int)sx; if (x0 > 319) x0 = 319;
  int y1 = y0 + 1 < 240 ? y0 + 1 : 239;
  int x1 = x0 + 1 < 320 ? x0 + 1 : 319;
  double wy = sy - (double)y0;
  double wx = sx - (double)x0;
  const float* base = input + (size_t)b * 76800;
  double g00 = base[y0 * 320 + x0], g01 = base[y0 * 320 + x1];
  double g10 = base[y1 * 320 + x0], g11 = base[y1 * 320 + x1];
  double v = g00 * (1.0 - wy) * (1.0 - wx) + g01 * (1.0 - wy) * wx
           + g10 * wy * (1.0 - wx) + g11 * wy * wx;
  return (float)v;
}

// byte-packed detection + precompute pick keys + ZERO all per-call counters
__global__ void k_detect(const unsigned* mw, unsigned* ws_u32) {
  __shared__ unsigned s_f;
  int tid = threadIdx.x;
  if (tid == 0) s_f = 0;
  if (tid < NPICK) ws_u32[WS_NCAND / 4 + tid] = 0;
  if (tid == 32) ws_u32[WS_DONE / 4] = 0;
  __syncthreads();
  unsigned f = 0;
  for (int i = tid; i < 16384; i += 256) {
    unsigned w = mw[i];
    if ((w & 0xFEFEFEFEu) == 0u && w > 1u) f = 1;   // only possible if byte-packed bools
  }
  if (f) atomicOr(&s_f, 1u);
  __syncthreads();
  if (tid == 0) ws_u32[WS_FLAG / 4] = s_f;
  if (tid < NPICK) {
    uint32_t k0, k1; pick_key(tid, k0, k1);
    ws_u32[WS_KEYS / 4 + tid * 2]     = k0;
    ws_u32[WS_KEYS / 4 + tid * 2 + 1] = k1;
  }
}

// fused scan: read masks once, 2 threefry per valid pixel, buffer candidates in
// LDS, ONE global atomic per (block,pick) to reserve output space.
__global__ __launch_bounds__(256)
void k_cand(const void* mym, const void* msk, unsigned* ws_u32, uint64_t* cand) {
  __shared__ uint64_t s_cand[4][CAP];
  __shared__ unsigned s_cnt[4];
  __shared__ unsigned s_base[4];
  int b = blockIdx.x / CHUNKS;
  int chunk = blockIdx.x % CHUNKS;
  int tid = threadIdx.x;
  if (tid < 4) s_cnt[tid] = 0;
  __syncthreads();
  unsigned bytef = ws_u32[WS_FLAG / 4];
  const unsigned* keys = ws_u32 + WS_KEYS / 4;
  uint32_t kk[4][2];
  for (int t = 0; t < 4; ++t) {
    kk[t][0] = keys[(b * 4 + t) * 2];
    kk[t][1] = keys[(b * 4 + t) * 2 + 1];
  }
  long base = (long)b * NPIX;
  int start = chunk * CHUNK_PX;

#define EMIT(my_, p) do {                                                     \
    int t0_ = (my_) ? 0 : 2;                                                  \
    uint32_t mA_ = rbits(kk[t0_][0], kk[t0_][1], (p)) >> 9;                   \
    if (mA_ < T0) {                                                           \
      unsigned s_ = atomicAdd(&s_cnt[t0_], 1u);                               \
      if (s_ < CAP) s_cand[t0_][s_] = ((uint64_t)mA_ << 19) | (uint32_t)(p);  \
    }                                                                         \
    uint32_t mB_ = rbits(kk[t0_ + 1][0], kk[t0_ + 1][1], (p)) >> 9;           \
    if (mB_ < T0) {                                                           \
      unsigned s_ = atomicAdd(&s_cnt[t0_ + 1], 1u);                           \
      if (s_ < CAP) s_cand[t0_ + 1][s_] = ((uint64_t)mB_ << 19) | (uint32_t)(p); \
    }                                                                         \
  } while (0)

  if (bytef) {
    const unsigned* myw = (const unsigned*)((const uint8_t*)mym + base + start);
    const unsigned* mkw = (const unsigned*)((const uint8_t*)msk + base + start);
    for (int it = 0; it < CHUNK_PX / 1024; ++it) {
      int wi = it * 256 + tid;
      unsigned wk = mkw[wi];
      if (wk == 0) continue;
      unsigned wm = myw[wi];
      int p0 = start + wi * 4;
      for (int s = 0; s < 4; ++s) {
        if (((wk >> (8 * s)) & 0xFFu) == 0u) continue;
        bool my_ = ((wm >> (8 * s)) & 0xFFu) != 0u;
        EMIT(my_, p0 + s);
      }
    }
  } else {
    const int* my4 = (const int*)mym;
    const int* mk4 = (const int*)msk;
    for (int p = start + tid; p < start + CHUNK_PX; p += 256) {
      if (mk4[base + p] == 0) continue;
      bool my_ = my4[base + p] != 0;
      EMIT(my_, p);
    }
  }
#undef EMIT
  __syncthreads();
  if (tid < 4) {
    unsigned c = s_cnt[tid]; if (c > CAP) c = CAP;
    s_cnt[tid] = c;
    s_base[tid] = atomicAdd(&ws_u32[WS_NCAND / 4 + b * 4 + tid], c);
  }
  __syncthreads();
  for (int pk = 0; pk < 4; ++pk) {
    unsigned c = s_cnt[pk], bs = s_base[pk];
    uint64_t* outp = cand + (size_t)(b * 4 + pk) * MAXCAND;
    for (unsigned i = tid; i < c; i += 256) {
      unsigned d = bs + i;
      if (d < MAXCAND) outp[d] = s_cand[pk][i];
    }
  }
}

// per pick: LDS histogram -> parallel prefix scan -> collect <=1024 survivors
// -> bitonic sort -> gather values in rank order
__global__ __launch_bounds__(1024)
void k_fsel(const float* input, const float* target, unsigned* ws_u32,
            const uint64_t* cand, float* vals) {
  __shared__ unsigned s_hist[FBINS];     // becomes inclusive cumsum
  __shared__ uint64_t s_sel[1024];
  __shared__ unsigned s_cnt, s_T;
  int tid = threadIdx.x;
  int pick = blockIdx.x;
  int b = pick >> 2, t = pick & 3;
  unsigned nc = ws_u32[WS_NCAND / 4 + pick];
  if (nc > MAXCAND) nc = MAXCAND;
  const uint64_t* cp = cand + (size_t)pick * MAXCAND;
  s_hist[tid] = 0;
  if (tid == 0) s_cnt = 0;
  __syncthreads();
  for (int i = tid; i < (int)nc; i += 1024) {
    unsigned m = (unsigned)(cp[i] >> 19);
    atomicAdd(&s_hist[m >> FSHIFT], 1u);
  }
  __syncthreads();
  // Hillis-Steele inclusive scan over 1024 bins
  for (int off = 1; off < FBINS; off <<= 1) {
    unsigned add = (tid >= off) ? s_hist[tid - off] : 0u;
    __syncthreads();
    s_hist[tid] += add;
    __syncthreads();
  }
  // threshold bin: first T with cum[T] >= SN
  if (s_hist[tid] >= SN && (tid == 0 || s_hist[tid - 1] < SN)) s_T = (unsigned)tid;
  __syncthreads();
  unsigned T = s_T;
  // collect all keys with bin <= T (count = cum[T], ~SN + few); order arbitrary
  for (int i = tid; i < (int)nc; i += 1024) {
    uint64_t k = cp[i];
    unsigned bin = ((unsigned)(k >> 19)) >> FSHIFT;
    if (bin <= T) {
      unsigned s = atomicAdd(&s_cnt, 1u);
      if (s < 1024) s_sel[s] = k;
    }
  }
  __syncthreads();
  unsigned cnt = s_cnt; if (cnt > 1024) cnt = 1024;
  if (tid >= (int)cnt) s_sel[tid] = ~0ULL;     // pad
  __syncthreads();
  // bitonic sort, ascending; keys unique -> sorted position == top_k rank
  for (int k = 2; k <= 1024; k <<= 1) {
    for (int j = k >> 1; j > 0; j >>= 1) {
      int ixj = tid ^ j;
      if (ixj > tid) {
        uint64_t a = s_sel[tid], bb = s_sel[ixj];
        bool up = ((tid & k) == 0);
        if ((a > bb) == up) { s_sel[tid] = bb; s_sel[ixj] = a; }
      }
      __syncthreads();
    }
  }
  if (tid < SN) {
    uint64_t key = s_sel[tid];
    int p = (int)(key & 0x7FFFFULL);
    float v = (t & 1) ? target[(long)b * NPIX + p] : bilinear_val(input, b, p);
    vals[(size_t)pick * SN + tid] = v;
  }
}

// pairwise loss partials + last-block final sum (deterministic: fixed read order)
__global__ __launch_bounds__(256)
void k_loss(const float* vals, float* partials, unsigned* done, float* out) {
  int bb = blockIdx.x / LCHUNKS;
  int ch = blockIdx.x % LCHUNKS;
  const float* ii = vals + (size_t)(4 * bb + 0) * SN;
  const float* it = vals + (size_t)(4 * bb + 1) * SN;
  const float* oi = vals + (size_t)(4 * bb + 2) * SN;
  const float* ot = vals + (size_t)(4 * bb + 3) * SN;
  __shared__ float s_oi[SN], s_ot[SN];
  for (int j = threadIdx.x; j < SN; j += 256) { s_oi[j] = oi[j]; s_ot[j] = ot[j]; }
  __syncthreads();
  float acc = 0.f;
  int a0 = ch * LROWS, a1 = a0 + LROWS;
  for (int a = a0; a < a1; ++a) {
    float iia = ii[a], ita = it[a];
    for (int j = threadIdx.x; j < SN; j += 256) {
      acc += fabsf(fabsf(iia - s_oi[j]) - fabsf(ita - s_ot[j]));
    }
  }
  __shared__ float s_red[256];
  s_red[threadIdx.x] = acc;
  __syncthreads();
  for (int s = 128; s > 0; s >>= 1) {
    if ((int)threadIdx.x < s) s_red[threadIdx.x] += s_red[threadIdx.x + s];
    __syncthreads();
  }
  __shared__ unsigned s_last;
  if (threadIdx.x == 0) {
    partials[blockIdx.x] = s_red[0];
    __threadfence();                            // partial visible device-wide
    s_last = atomicAdd(done, 1u);
  }
  __syncthreads();
  if (s_last != (unsigned)(gridDim.x - 1)) return;
  // last block: device-scope atomic reads of all partials, fixed order
  if (threadIdx.x < 64) {
    double acc2 = 0.0;
    for (int i = threadIdx.x; i < NLOSS; i += 64)
      acc2 += (double)atomicAdd(&partials[i], 0.0f);
    for (int off = 32; off > 0; off >>= 1)
      acc2 += __shfl_down(acc2, off, 64);
    if (threadIdx.x == 0) out[0] = (float)(acc2 * 1e-6);
  }
}

extern "C" void kernel_launch(void* const* d_in, const int* in_sizes, int n_in,
                              void* d_out, int out_size, void* d_ws, size_t ws_size,
                              hipStream_t stream) {
  const float* input  = (const float*)d_in[0];
  const float* target = (const float*)d_in[1];
  const void* mym = d_in[2];
  const void* msk = d_in[3];
  (void)in_sizes; (void)n_in; (void)out_size; (void)ws_size;

  unsigned* ws_u32 = (unsigned*)d_ws;
  uint64_t* cand  = (uint64_t*)((char*)d_ws + WS_CAND);
  float* vals     = (float*)((char*)d_ws + WS_VALS);
  float* partials = (float*)((char*)d_ws + WS_PART);
  unsigned* done  = ws_u32 + WS_DONE / 4;

  k_detect<<<1, 256, 0, stream>>>((const unsigned*)mym, ws_u32);
  k_cand<<<B_ * CHUNKS, 256, 0, stream>>>(mym, msk, ws_u32, cand);
  k_fsel<<<NPICK, 1024, 0, stream>>>(input, target, ws_u32, cand, vals);
  k_loss<<<B_ * LCHUNKS, 256, 0, stream>>>(vals, partials, done, (float*)d_out);
}

// Round 5
// 59.090 us; speedup vs baseline: 9.4972x; 1.3335x over previous
//
#include <hip/hip_runtime.h>
#include <stdint.h>

#define B_       8
#define NPIX     307200        // 480*640
#define SN       1000
#define NPICK    32            // 8 batches * 4 picks
#define T0BITS   17
#define T0       (1u << T0BITS)     // candidate filter: m < 2^17 (~1/64 of valid)
#define CHUNKS   150
#define CHUNK_PX 2048
#define SLOTS    64                 // fixed per-(block,pick) candidate slots
#define NSLOT    (CHUNKS * SLOTS)   // 9600 slots per pick
#define FBINS    512
#define BCAP     24                 // bucket capacity (P(overflow) ~ 8e-6 total)
#define LCHUNKS  25
#define LROWS    (SN / LCHUNKS)     // 40
#define NLOSS    (B_ * LCHUNKS)     // 200

// ws layout (bytes)
#define WS_DONE  0                          // 4
#define WS_CAND  512                        // 32*9600*8 = 2457600
#define WS_VALS  (512 + 2457600)            // 32*1000*4 = 128000
#define WS_PART  (WS_VALS + 128000)         // 200*4

// ---- Threefry-2x32-20, matches jax/_src/prng.py ----
__device__ __forceinline__ void tf2x32(uint32_t k0, uint32_t k1,
                                       uint32_t x0, uint32_t x1,
                                       uint32_t& o0, uint32_t& o1) {
  uint32_t ks2 = k0 ^ k1 ^ 0x1BD11BDAu;
  x0 += k0; x1 += k1;
#define RR(r) { x0 += x1; x1 = (x1 << (r)) | (x1 >> (32 - (r))); x1 ^= x0; }
  RR(13) RR(15) RR(26) RR(6)
  x0 += k1; x1 += ks2 + 1u;
  RR(17) RR(29) RR(16) RR(24)
  x0 += ks2; x1 += k0 + 2u;
  RR(13) RR(15) RR(26) RR(6)
  x0 += k0; x1 += k1 + 3u;
  RR(17) RR(29) RR(16) RR(24)
  x0 += k1; x1 += ks2 + 4u;
  RR(13) RR(15) RR(26) RR(6)
  x0 += ks2; x1 += k0 + 5u;
#undef RR
  o0 = x0; o1 = x1;
}

__device__ __forceinline__ void pick_key(int pick, uint32_t& k0, uint32_t& k1) {
  tf2x32(0u, 42u, 0u, (uint32_t)pick, k0, k1);
}

__device__ __forceinline__ uint32_t rbits(uint32_t k0, uint32_t k1, int p) {
  uint32_t o0, o1;
  tf2x32(k0, k1, 0u, (uint32_t)p, o0, o1);
  return o0 ^ o1;
}

// align-corners bilinear of input (8,1,240,320) at flat out-pixel p of (480,640)
__device__ float bilinear_val(const float* input, int b, int p) {
  int oy = p / 640;
  int ox = p - oy * 640;
  double sy = ((double)oy * 239.0) / 479.0;
  double sx = ((double)ox * 319.0) / 639.0;
  int y0 = (int)sy; if (y0 > 239) y0 = 239;
  int x0 = (int)sx; if (x0 > 319) x0 = 319;
  int y1 = y0 + 1 < 240 ? y0 + 1 : 239;
  int x1 = x0 + 1 < 320 ? x0 + 1 : 319;
  double wy = sy - (double)y0;
  double wx = sx - (double)x0;
  const float* base = input + (size_t)b * 76800;
  double g00 = base[y0 * 320 + x0], g01 = base[y0 * 320 + x1];
  double g10 = base[y1 * 320 + x0], g11 = base[y1 * 320 + x1];
  double v = g00 * (1.0 - wy) * (1.0 - wx) + g01 * (1.0 - wy) * wx
           + g10 * wy * (1.0 - wx) + g11 * wy * wx;
  return (float)v;
}

// fused: per-block byte-format detect + mask scan + threefry filter into
// fixed per-(block,pick) slot segments. No global atomics, no pre-zeroing.
__global__ __launch_bounds__(256)
void k_cand(const void* mym, const void* msk, unsigned* done, uint64_t* cand) {
  __shared__ uint64_t s_cand[4][SLOTS];
  __shared__ unsigned s_cnt[4];
  __shared__ unsigned s_bytef;
  __shared__ unsigned s_kk[4][2];
  int b = blockIdx.x / CHUNKS;
  int chunk = blockIdx.x % CHUNKS;
  int tid = threadIdx.x;
  if (blockIdx.x == 0 && tid == 0) *done = 0;   // reset for k_loss (stream-ordered)
  if (tid < 4) {
    s_cnt[tid] = 0;
    uint32_t k0, k1; pick_key(b * 4 + tid, k0, k1);
    s_kk[tid][0] = k0; s_kk[tid][1] = k1;
  }
  if (tid == 4) s_bytef = 0;
  ((uint64_t*)s_cand)[tid] = ~0ULL;             // sentinel-fill all 256 slots
  long base = (long)b * NPIX;
  int start = chunk * CHUNK_PX;
  // detect on this block's msk window at BYTE offsets (in-bounds for both dtypes):
  // a word with all bytes in {0,1} and value>1 can only be byte-packed bools.
  {
    const unsigned* w = (const unsigned*)((const uint8_t*)msk + base + start);
    unsigned a0 = w[tid], a1 = w[tid + 256];
    unsigned f = ((a0 & 0xFEFEFEFEu) == 0u && a0 > 1u) ||
                 ((a1 & 0xFEFEFEFEu) == 0u && a1 > 1u);
    if (f) atomicOr(&s_bytef, 1u);
  }
  __syncthreads();
  unsigned bytef = s_bytef;
  uint32_t kk00 = s_kk[0][0], kk01 = s_kk[0][1];
  uint32_t kk10 = s_kk[1][0], kk11 = s_kk[1][1];
  uint32_t kk20 = s_kk[2][0], kk21 = s_kk[2][1];
  uint32_t kk30 = s_kk[3][0], kk31 = s_kk[3][1];

#define EMIT(my_, p) do {                                                       \
    int t0_ = (my_) ? 0 : 2;                                                    \
    uint32_t ka0_ = (my_) ? kk00 : kk20, ka1_ = (my_) ? kk01 : kk21;            \
    uint32_t kb0_ = (my_) ? kk10 : kk30, kb1_ = (my_) ? kk11 : kk31;            \
    uint32_t mA_ = rbits(ka0_, ka1_, (p)) >> 9;                                 \
    if (mA_ < T0) {                                                             \
      unsigned s_ = atomicAdd(&s_cnt[t0_], 1u);                                 \
      if (s_ < SLOTS) s_cand[t0_][s_] = ((uint64_t)mA_ << 19) | (uint32_t)(p);  \
    }                                                                           \
    uint32_t mB_ = rbits(kb0_, kb1_, (p)) >> 9;                                 \
    if (mB_ < T0) {                                                             \
      unsigned s_ = atomicAdd(&s_cnt[t0_ + 1], 1u);                             \
      if (s_ < SLOTS) s_cand[t0_ + 1][s_] = ((uint64_t)mB_ << 19) | (uint32_t)(p); \
    }                                                                           \
  } while (0)

  if (bytef) {
    const uint2* mkw = (const uint2*)((const uint8_t*)msk + base + start);
    const uint2* myw = (const uint2*)((const uint8_t*)mym + base + start);
    uint2 wk = mkw[tid];                        // 256 threads x 8 px = whole chunk
    uint2 wm = myw[tid];
    int p0 = start + tid * 8;
    #pragma unroll
    for (int s = 0; s < 4; ++s)
      if ((wk.x >> (8 * s)) & 0xFFu) EMIT(((wm.x >> (8 * s)) & 0xFFu) != 0u, p0 + s);
    #pragma unroll
    for (int s = 0; s < 4; ++s)
      if ((wk.y >> (8 * s)) & 0xFFu) EMIT(((wm.y >> (8 * s)) & 0xFFu) != 0u, p0 + 4 + s);
  } else {
    const int4* mk4 = (const int4*)((const int*)msk + base + start);
    const int4* my4 = (const int4*)((const int*)mym + base + start);
    for (int it = 0; it < 2; ++it) {
      int idx = it * 256 + tid;
      int4 k = mk4[idx];
      int4 m = my4[idx];
      int p0 = start + idx * 4;
      if (k.x) EMIT(m.x != 0, p0);
      if (k.y) EMIT(m.y != 0, p0 + 1);
      if (k.z) EMIT(m.z != 0, p0 + 2);
      if (k.w) EMIT(m.w != 0, p0 + 3);
    }
  }
#undef EMIT
  __syncthreads();
  // copy out fixed segment: thread t -> (pick t>>6, slot t&63), coalesced
  int pk = tid >> 6, sl = tid & 63;
  cand[((size_t)(b * 4 + pk) * CHUNKS + chunk) * SLOTS + sl] = s_cand[pk][sl];
}

// per pick: bucket-scatter (512 bins) -> wave prefix scan -> exact rank via
// in-bin compares -> gather values at rank position. ~5 barriers total.
__global__ __launch_bounds__(1024)
void k_fsel(const float* input, const float* target, const uint64_t* cand,
            float* vals) {
  __shared__ uint32_t s_bkt[FBINS][BCAP];   // 48 KB
  __shared__ unsigned s_hcnt[FBINS];
  __shared__ unsigned s_cum[FBINS];         // exclusive cumsum
  __shared__ unsigned s_wsum[FBINS / 64];
  __shared__ unsigned s_T;
  int tid = threadIdx.x, pick = blockIdx.x;
  int b = pick >> 2, t = pick & 3;
  if (tid < FBINS) s_hcnt[tid] = 0;
  if (tid == 0) s_T = 0xFFFFu;
  __syncthreads();
  const uint64_t* cp = cand + (size_t)pick * NSLOT;
  // pass 1: histogram + bucket scatter (key = (m&255)<<19 | p, unique 27-bit)
  for (int i = tid; i < NSLOT; i += 1024) {
    uint64_t k = cp[i];
    if (k == ~0ULL) continue;
    unsigned m = (unsigned)(k >> 19);
    unsigned bin = m >> 8;
    unsigned w = ((m & 255u) << 19) | (unsigned)(k & 0x7FFFFu);
    unsigned s = atomicAdd(&s_hcnt[bin], 1u);
    if (s < BCAP) s_bkt[bin][s] = w;
  }
  __syncthreads();
  // wave-level inclusive scan over 512 bins (waves 0..7)
  unsigned incl = 0;
  if (tid < FBINS) {
    unsigned x = s_hcnt[tid];
    #pragma unroll
    for (int off = 1; off < 64; off <<= 1) {
      unsigned y = __shfl_up(x, off, 64);
      if ((tid & 63) >= off) x += y;
    }
    if ((tid & 63) == 63) s_wsum[tid >> 6] = x;
    incl = x;
  }
  __syncthreads();
  if (tid == 0) {
    unsigned run = 0;
    for (int wv = 0; wv < FBINS / 64; ++wv) {
      unsigned c = s_wsum[wv]; s_wsum[wv] = run; run += c;
    }
  }
  __syncthreads();
  if (tid < FBINS) {
    incl += s_wsum[tid >> 6];
    unsigned cnt = s_hcnt[tid];
    unsigned excl = incl - cnt;
    s_cum[tid] = excl;
    if (incl >= SN && excl < SN) s_T = (unsigned)tid;  // unique threshold bin
  }
  __syncthreads();
  unsigned T = s_T;
  // pass 2: rank = excl_cum[bin] + #same-bin-smaller; write if rank < SN
  for (int i = tid; i < NSLOT; i += 1024) {
    uint64_t k = cp[i];
    if (k == ~0ULL) continue;
    unsigned m = (unsigned)(k >> 19);
    unsigned bin = m >> 8;
    if (bin > T) continue;
    unsigned w = ((m & 255u) << 19) | (unsigned)(k & 0x7FFFFu);
    unsigned cnt = s_hcnt[bin]; if (cnt > BCAP) cnt = BCAP;
    unsigned local = 0;
    for (unsigned j = 0; j < cnt; ++j) local += (s_bkt[bin][j] < w) ? 1u : 0u;
    unsigned r = s_cum[bin] + local;
    if (r < SN) {
      int p = (int)(k & 0x7FFFFULL);
      float v = (t & 1) ? target[(long)b * NPIX + p] : bilinear_val(input, b, p);
      vals[(size_t)pick * SN + r] = v;
    }
  }
}

// pairwise loss partials + last-block final sum (deterministic: fixed read order)
__global__ __launch_bounds__(256)
void k_loss(const float* vals, float* partials, unsigned* done, float* out) {
  int bb = blockIdx.x / LCHUNKS;
  int ch = blockIdx.x % LCHUNKS;
  const float* ii = vals + (size_t)(4 * bb + 0) * SN;
  const float* it = vals + (size_t)(4 * bb + 1) * SN;
  const float* oi = vals + (size_t)(4 * bb + 2) * SN;
  const float* ot = vals + (size_t)(4 * bb + 3) * SN;
  __shared__ float s_oi[SN], s_ot[SN];
  for (int j = threadIdx.x; j < SN; j += 256) { s_oi[j] = oi[j]; s_ot[j] = ot[j]; }
  __syncthreads();
  float acc = 0.f;
  int a0 = ch * LROWS, a1 = a0 + LROWS;
  for (int a = a0; a < a1; ++a) {
    float iia = ii[a], ita = it[a];
    for (int j = threadIdx.x; j < SN; j += 256) {
      acc += fabsf(fabsf(iia - s_oi[j]) - fabsf(ita - s_ot[j]));
    }
  }
  __shared__ float s_red[256];
  s_red[threadIdx.x] = acc;
  __syncthreads();
  for (int s = 128; s > 0; s >>= 1) {
    if ((int)threadIdx.x < s) s_red[threadIdx.x] += s_red[threadIdx.x + s];
    __syncthreads();
  }
  __shared__ unsigned s_last;
  if (threadIdx.x == 0) {
    partials[blockIdx.x] = s_red[0];
    __threadfence();                            // partial visible device-wide
    s_last = atomicAdd(done, 1u);
  }
  __syncthreads();
  if (s_last != (unsigned)(gridDim.x - 1)) return;
  // last block: device-scope atomic reads of all partials, fixed order
  if (threadIdx.x < 64) {
    double acc2 = 0.0;
    for (int i = threadIdx.x; i < NLOSS; i += 64)
      acc2 += (double)atomicAdd(&partials[i], 0.0f);
    for (int off = 32; off > 0; off >>= 1)
      acc2 += __shfl_down(acc2, off, 64);
    if (threadIdx.x == 0) out[0] = (float)(acc2 * 1e-6);
  }
}

extern "C" void kernel_launch(void* const* d_in, const int* in_sizes, int n_in,
                              void* d_out, int out_size, void* d_ws, size_t ws_size,
                              hipStream_t stream) {
  const float* input  = (const float*)d_in[0];
  const float* target = (const float*)d_in[1];
  const void* mym = d_in[2];
  const void* msk = d_in[3];
  (void)in_sizes; (void)n_in; (void)out_size; (void)ws_size;

  unsigned* ws_u32 = (unsigned*)d_ws;
  unsigned* done  = ws_u32 + WS_DONE / 4;
  uint64_t* cand  = (uint64_t*)((char*)d_ws + WS_CAND);
  float* vals     = (float*)((char*)d_ws + WS_VALS);
  float* partials = (float*)((char*)d_ws + WS_PART);

  k_cand<<<B_ * CHUNKS, 256, 0, stream>>>(mym, msk, done, cand);
  k_fsel<<<NPICK, 1024, 0, stream>>>(input, target, cand, vals);
  k_loss<<<NLOSS, 256, 0, stream>>>(vals, partials, done, (float*)d_out);
}

// Round 6
// 49.454 us; speedup vs baseline: 11.3478x; 1.1949x over previous
//
#include <hip/hip_runtime.h>
#include <stdint.h>

#define B_       8
#define NPIX     307200        // 480*640
#define SN       1000
#define NPICK    32            // 8 batches * 4 picks
#define T0BITS   17
#define T0       (1u << T0BITS)     // candidate filter: m < 2^17 (~1/64 of valid)
#define CHUNKS   150
#define CHUNK_PX 2048
#define SLOTS    64                 // fixed per-(block,pick) candidate slots
#define NSLOT    (CHUNKS * SLOTS)   // 9600 slots per pick
#define FBINS    512
#define BCAP     24                 // bucket capacity (P(overflow) ~ 1e-5 total)
#define LCHUNKS  25
#define LROWS    (SN / LCHUNKS)     // 40
#define NLOSS    (B_ * LCHUNKS)     // 200

// ws layout (bytes)
#define WS_DONE  0                          // 4
#define WS_CAND  512                        // 32*9600*4 = 1228800
#define WS_VALS  (512 + 1228800)            // 32*1000*4 = 128000
#define WS_PART  (WS_VALS + 128000)         // 200*4

// ---- Threefry-2x32-20, matches jax/_src/prng.py ----
__device__ __forceinline__ void tf2x32(uint32_t k0, uint32_t k1,
                                       uint32_t x0, uint32_t x1,
                                       uint32_t& o0, uint32_t& o1) {
  uint32_t ks2 = k0 ^ k1 ^ 0x1BD11BDAu;
  x0 += k0; x1 += k1;
#define RR(r) { x0 += x1; x1 = (x1 << (r)) | (x1 >> (32 - (r))); x1 ^= x0; }
  RR(13) RR(15) RR(26) RR(6)
  x0 += k1; x1 += ks2 + 1u;
  RR(17) RR(29) RR(16) RR(24)
  x0 += ks2; x1 += k0 + 2u;
  RR(13) RR(15) RR(26) RR(6)
  x0 += k0; x1 += k1 + 3u;
  RR(17) RR(29) RR(16) RR(24)
  x0 += k1; x1 += ks2 + 4u;
  RR(13) RR(15) RR(26) RR(6)
  x0 += ks2; x1 += k0 + 5u;
#undef RR
  o0 = x0; o1 = x1;
}

__device__ __forceinline__ void pick_key(int pick, uint32_t& k0, uint32_t& k1) {
  tf2x32(0u, 42u, 0u, (uint32_t)pick, k0, k1);
}

__device__ __forceinline__ uint32_t rbits(uint32_t k0, uint32_t k1, int p) {
  uint32_t o0, o1;
  tf2x32(k0, k1, 0u, (uint32_t)p, o0, o1);
  return o0 ^ o1;
}

// align-corners bilinear of input (8,1,240,320) at flat out-pixel p of (480,640)
__device__ float bilinear_val(const float* input, int b, int p) {
  int oy = p / 640;
  int ox = p - oy * 640;
  double sy = ((double)oy * 239.0) / 479.0;
  double sx = ((double)ox * 319.0) / 639.0;
  int y0 = (int)sy; if (y0 > 239) y0 = 239;
  int x0 = (int)sx; if (x0 > 319) x0 = 319;
  int y1 = y0 + 1 < 240 ? y0 + 1 : 239;
  int x1 = x0 + 1 < 320 ? x0 + 1 : 319;
  double wy = sy - (double)y0;
  double wx = sx - (double)x0;
  const float* base = input + (size_t)b * 76800;
  double g00 = base[y0 * 320 + x0], g01 = base[y0 * 320 + x1];
  double g10 = base[y1 * 320 + x0], g11 = base[y1 * 320 + x1];
  double v = g00 * (1.0 - wy) * (1.0 - wx) + g01 * (1.0 - wy) * wx
           + g10 * wy * (1.0 - wx) + g11 * wy * wx;
  return (float)v;
}

// fused: per-block byte-format detect + mask scan + threefry filter into
// fixed per-(block,pick) uint32 slot segments. No global atomics.
// packed candidate: (m << 11) | (p & 2047), m < 2^17; sentinel 0xFFFFFFFF.
__global__ __launch_bounds__(256)
void k_cand(const void* mym, const void* msk, unsigned* done, uint32_t* cand) {
  __shared__ uint32_t s_cand[4][SLOTS];
  __shared__ unsigned s_cnt[4];
  __shared__ unsigned s_bytef;
  __shared__ unsigned s_kk[4][2];
  int b = blockIdx.x / CHUNKS;
  int chunk = blockIdx.x % CHUNKS;
  int tid = threadIdx.x;
  if (blockIdx.x == 0 && tid == 0) *done = 0;   // reset for k_loss (stream-ordered)
  if (tid < 4) {
    s_cnt[tid] = 0;
    uint32_t k0, k1; pick_key(b * 4 + tid, k0, k1);
    s_kk[tid][0] = k0; s_kk[tid][1] = k1;
  }
  if (tid == 4) s_bytef = 0;
  ((uint32_t*)s_cand)[tid] = 0xFFFFFFFFu;       // sentinel-fill all 256 slots
  long base = (long)b * NPIX;
  int start = chunk * CHUNK_PX;
  // detect on this block's msk window at BYTE offsets (in-bounds for both dtypes):
  // a word with all bytes in {0,1} and value>1 can only be byte-packed bools.
  {
    const unsigned* w = (const unsigned*)((const uint8_t*)msk + base + start);
    unsigned a0 = w[tid], a1 = w[tid + 256];
    unsigned f = ((a0 & 0xFEFEFEFEu) == 0u && a0 > 1u) ||
                 ((a1 & 0xFEFEFEFEu) == 0u && a1 > 1u);
    if (f) atomicOr(&s_bytef, 1u);
  }
  __syncthreads();
  unsigned bytef = s_bytef;
  uint32_t kk00 = s_kk[0][0], kk01 = s_kk[0][1];
  uint32_t kk10 = s_kk[1][0], kk11 = s_kk[1][1];
  uint32_t kk20 = s_kk[2][0], kk21 = s_kk[2][1];
  uint32_t kk30 = s_kk[3][0], kk31 = s_kk[3][1];

#define EMIT(my_, p) do {                                                       \
    int t0_ = (my_) ? 0 : 2;                                                    \
    uint32_t ka0_ = (my_) ? kk00 : kk20, ka1_ = (my_) ? kk01 : kk21;            \
    uint32_t kb0_ = (my_) ? kk10 : kk30, kb1_ = (my_) ? kk11 : kk31;            \
    uint32_t mA_ = rbits(ka0_, ka1_, (p)) >> 9;                                 \
    if (mA_ < T0) {                                                             \
      unsigned s_ = atomicAdd(&s_cnt[t0_], 1u);                                 \
      if (s_ < SLOTS) s_cand[t0_][s_] = (mA_ << 11) | ((unsigned)(p) & 2047u);  \
    }                                                                           \
    uint32_t mB_ = rbits(kb0_, kb1_, (p)) >> 9;                                 \
    if (mB_ < T0) {                                                             \
      unsigned s_ = atomicAdd(&s_cnt[t0_ + 1], 1u);                             \
      if (s_ < SLOTS) s_cand[t0_ + 1][s_] = (mB_ << 11) | ((unsigned)(p) & 2047u); \
    }                                                                           \
  } while (0)

  if (bytef) {
    const uint2* mkw = (const uint2*)((const uint8_t*)msk + base + start);
    const uint2* myw = (const uint2*)((const uint8_t*)mym + base + start);
    uint2 wk = mkw[tid];                        // 256 threads x 8 px = whole chunk
    uint2 wm = myw[tid];
    int p0 = start + tid * 8;
    #pragma unroll
    for (int s = 0; s < 4; ++s)
      if ((wk.x >> (8 * s)) & 0xFFu) EMIT(((wm.x >> (8 * s)) & 0xFFu) != 0u, p0 + s);
    #pragma unroll
    for (int s = 0; s < 4; ++s)
      if ((wk.y >> (8 * s)) & 0xFFu) EMIT(((wm.y >> (8 * s)) & 0xFFu) != 0u, p0 + 4 + s);
  } else {
    const int4* mk4 = (const int4*)((const int*)msk + base + start);
    const int4* my4 = (const int4*)((const int*)mym + base + start);
    for (int it = 0; it < 2; ++it) {
      int idx = it * 256 + tid;
      int4 k = mk4[idx];
      int4 m = my4[idx];
      int p0 = start + idx * 4;
      if (k.x) EMIT(m.x != 0, p0);
      if (k.y) EMIT(m.y != 0, p0 + 1);
      if (k.z) EMIT(m.z != 0, p0 + 2);
      if (k.w) EMIT(m.w != 0, p0 + 3);
    }
  }
#undef EMIT
  __syncthreads();
  // copy out fixed segment: thread t -> (pick t>>6, slot t&63), coalesced
  int pk = tid >> 6, sl = tid & 63;
  cand[((size_t)(b * 4 + pk) * CHUNKS + chunk) * SLOTS + sl] = s_cand[pk][sl];
}

// per pick: bucket-scatter (512 bins) -> wave prefix scan -> exact rank via
// in-bin compares -> gather values at rank position. ~5 barriers total.
__global__ __launch_bounds__(1024)
void k_fsel(const float* input, const float* target, const uint32_t* cand,
            float* vals) {
  __shared__ uint32_t s_bkt[FBINS][BCAP];   // 48 KB
  __shared__ unsigned s_hcnt[FBINS];
  __shared__ unsigned s_cum[FBINS];         // exclusive cumsum
  __shared__ unsigned s_wsum[FBINS / 64];
  __shared__ unsigned s_T;
  int tid = threadIdx.x, pick = blockIdx.x;
  int b = pick >> 2, t = pick & 3;
  if (tid < FBINS) s_hcnt[tid] = 0;
  if (tid == 0) s_T = 0xFFFFu;
  __syncthreads();
  const uint32_t* cp = cand + (size_t)pick * NSLOT;
  // pass 1: histogram + bucket scatter (w27 = (m&255)<<19 | p, unique 27-bit)
  for (int i = tid; i < NSLOT; i += 1024) {
    uint32_t w = cp[i];
    if (w == 0xFFFFFFFFu) continue;
    unsigned m = w >> 11;
    unsigned bin = m >> 8;                       // m < 2^17 -> bin < 512
    unsigned p = ((unsigned)i >> 6) * 2048u + (w & 2047u);
    unsigned w27 = ((m & 255u) << 19) | p;
    unsigned s = atomicAdd(&s_hcnt[bin], 1u);
    if (s < BCAP) s_bkt[bin][s] = w27;
  }
  __syncthreads();
  // wave-level inclusive scan over 512 bins (waves 0..7)
  unsigned incl = 0;
  if (tid < FBINS) {
    unsigned x = s_hcnt[tid];
    #pragma unroll
    for (int off = 1; off < 64; off <<= 1) {
      unsigned y = __shfl_up(x, off, 64);
      if ((tid & 63) >= off) x += y;
    }
    if ((tid & 63) == 63) s_wsum[tid >> 6] = x;
    incl = x;
  }
  __syncthreads();
  if (tid == 0) {
    unsigned run = 0;
    for (int wv = 0; wv < FBINS / 64; ++wv) {
      unsigned c = s_wsum[wv]; s_wsum[wv] = run; run += c;
    }
  }
  __syncthreads();
  if (tid < FBINS) {
    incl += s_wsum[tid >> 6];
    unsigned cnt = s_hcnt[tid];
    unsigned excl = incl - cnt;
    s_cum[tid] = excl;
    if (incl >= SN && excl < SN) s_T = (unsigned)tid;  // unique threshold bin
  }
  __syncthreads();
  unsigned T = s_T;
  // pass 2: rank = excl_cum[bin] + #same-bin-smaller; write if rank < SN
  for (int i = tid; i < NSLOT; i += 1024) {
    uint32_t w = cp[i];
    if (w == 0xFFFFFFFFu) continue;
    unsigned m = w >> 11;
    unsigned bin = m >> 8;
    if (bin > T) continue;
    unsigned p = ((unsigned)i >> 6) * 2048u + (w & 2047u);
    unsigned w27 = ((m & 255u) << 19) | p;
    unsigned cnt = s_hcnt[bin]; if (cnt > BCAP) cnt = BCAP;
    unsigned local = 0;
    for (unsigned j = 0; j < cnt; ++j) local += (s_bkt[bin][j] < w27) ? 1u : 0u;
    unsigned r = s_cum[bin] + local;
    if (r < SN) {
      float v = (t & 1) ? target[(long)b * NPIX + (int)p]
                        : bilinear_val(input, b, (int)p);
      vals[(size_t)pick * SN + r] = v;
    }
  }
}

// pairwise loss partials + last-block final sum (deterministic: fixed read order)
__global__ __launch_bounds__(256)
void k_loss(const float* vals, float* partials, unsigned* done, float* out) {
  int bb = blockIdx.x / LCHUNKS;
  int ch = blockIdx.x % LCHUNKS;
  const float* ii = vals + (size_t)(4 * bb + 0) * SN;
  const float* it = vals + (size_t)(4 * bb + 1) * SN;
  const float* oi = vals + (size_t)(4 * bb + 2) * SN;
  const float* ot = vals + (size_t)(4 * bb + 3) * SN;
  __shared__ float s_oi[SN], s_ot[SN];
  __shared__ float s_ii[LROWS], s_it[LROWS];
  int tid = threadIdx.x;
  int a0 = ch * LROWS;
  for (int j = tid; j < SN; j += 256) { s_oi[j] = oi[j]; s_ot[j] = ot[j]; }
  if (tid < LROWS) s_ii[tid] = ii[a0 + tid];
  else if (tid >= 64 && tid < 64 + LROWS) s_it[tid - 64] = it[a0 + tid - 64];
  __syncthreads();
  float acc = 0.f;
  if (tid < 250) {
    float4 o4 = ((const float4*)s_oi)[tid];       // one-time LDS b128 reads;
    float4 t4 = ((const float4*)s_ot)[tid];       // inner loop is pure VALU
    #pragma unroll 8
    for (int a = 0; a < LROWS; ++a) {
      float iia = s_ii[a], ita = s_it[a];         // LDS broadcast (same addr)
      acc += fabsf(fabsf(iia - o4.x) - fabsf(ita - t4.x));
      acc += fabsf(fabsf(iia - o4.y) - fabsf(ita - t4.y));
      acc += fabsf(fabsf(iia - o4.z) - fabsf(ita - t4.z));
      acc += fabsf(fabsf(iia - o4.w) - fabsf(ita - t4.w));
    }
  }
  __shared__ float s_red[256];
  s_red[tid] = acc;
  __syncthreads();
  for (int s = 128; s > 0; s >>= 1) {
    if (tid < s) s_red[tid] += s_red[tid + s];
    __syncthreads();
  }
  __shared__ unsigned s_last;
  if (tid == 0) {
    partials[blockIdx.x] = s_red[0];
    __threadfence();                              // partial visible device-wide
    s_last = atomicAdd(done, 1u);
  }
  __syncthreads();
  if (s_last != (unsigned)(gridDim.x - 1)) return;
  // last block: device-scope atomic reads of all partials, fixed order
  if (tid < 64) {
    double acc2 = 0.0;
    for (int i = tid; i < NLOSS; i += 64)
      acc2 += (double)atomicAdd(&partials[i], 0.0f);
    for (int off = 32; off > 0; off >>= 1)
      acc2 += __shfl_down(acc2, off, 64);
    if (tid == 0) out[0] = (float)(acc2 * 1e-6);
  }
}

extern "C" void kernel_launch(void* const* d_in, const int* in_sizes, int n_in,
                              void* d_out, int out_size, void* d_ws, size_t ws_size,
                              hipStream_t stream) {
  const float* input  = (const float*)d_in[0];
  const float* target = (const float*)d_in[1];
  const void* mym = d_in[2];
  const void* msk = d_in[3];
  (void)in_sizes; (void)n_in; (void)out_size; (void)ws_size;

  unsigned* ws_u32 = (unsigned*)d_ws;
  unsigned* done  = ws_u32 + WS_DONE / 4;
  uint32_t* cand  = (uint32_t*)((char*)d_ws + WS_CAND);
  float* vals     = (float*)((char*)d_ws + WS_VALS);
  float* partials = (float*)((char*)d_ws + WS_PART);

  k_cand<<<B_ * CHUNKS, 256, 0, stream>>>(mym, msk, done, cand);
  k_fsel<<<NPICK, 1024, 0, stream>>>(input, target, cand, vals);
  k_loss<<<NLOSS, 256, 0, stream>>>(vals, partials, done, (float*)d_out);
}

// Round 7
// 46.410 us; speedup vs baseline: 12.0921x; 1.0656x over previous
//
#include <hip/hip_runtime.h>
#include <stdint.h>

#define B_       8
#define NPIX     307200        // 480*640
#define SN       1000
#define NPICK    32            // 8 batches * 4 picks
#define T0BITS   17
#define T0       (1u << T0BITS)     // candidate filter: m < 2^17 (~1/64 of valid)
#define CHUNKS   150
#define CHUNK_PX 2048
#define SLOTS    64                 // fixed per-(block,pick) candidate slots
#define NSLOT    (CHUNKS * SLOTS)   // 9600 slots per pick
#define FBINS    512
#define BCAP     24                 // bucket capacity (P(overflow) ~ 1e-5 total)
#define LCHUNKS  25
#define LROWS    (SN / LCHUNKS)     // 40
#define NLOSS    (B_ * LCHUNKS)     // 200

// ws layout (bytes)
#define WS_DONE  0                          // 4
#define WS_CAND  512                        // 32*9600*4 = 1228800
#define WS_VALS  (512 + 1228800)            // 32*1000*4 = 128000
#define WS_PART  (WS_VALS + 128000)         // 200*4

// ---- Threefry-2x32-20, matches jax/_src/prng.py ----
__device__ __forceinline__ void tf2x32(uint32_t k0, uint32_t k1,
                                       uint32_t x0, uint32_t x1,
                                       uint32_t& o0, uint32_t& o1) {
  uint32_t ks2 = k0 ^ k1 ^ 0x1BD11BDAu;
  x0 += k0; x1 += k1;
#define RR(r) { x0 += x1; x1 = (x1 << (r)) | (x1 >> (32 - (r))); x1 ^= x0; }
  RR(13) RR(15) RR(26) RR(6)
  x0 += k1; x1 += ks2 + 1u;
  RR(17) RR(29) RR(16) RR(24)
  x0 += ks2; x1 += k0 + 2u;
  RR(13) RR(15) RR(26) RR(6)
  x0 += k0; x1 += k1 + 3u;
  RR(17) RR(29) RR(16) RR(24)
  x0 += k1; x1 += ks2 + 4u;
  RR(13) RR(15) RR(26) RR(6)
  x0 += ks2; x1 += k0 + 5u;
#undef RR
  o0 = x0; o1 = x1;
}

__device__ __forceinline__ void pick_key(int pick, uint32_t& k0, uint32_t& k1) {
  tf2x32(0u, 42u, 0u, (uint32_t)pick, k0, k1);
}

__device__ __forceinline__ uint32_t rbits(uint32_t k0, uint32_t k1, int p) {
  uint32_t o0, o1;
  tf2x32(k0, k1, 0u, (uint32_t)p, o0, o1);
  return o0 ^ o1;
}

// align-corners bilinear of input (8,1,240,320) at flat out-pixel p of (480,640)
__device__ float bilinear_val(const float* __restrict__ input, int b, int p) {
  int oy = p / 640;
  int ox = p - oy * 640;
  double sy = ((double)oy * 239.0) / 479.0;
  double sx = ((double)ox * 319.0) / 639.0;
  int y0 = (int)sy; if (y0 > 239) y0 = 239;
  int x0 = (int)sx; if (x0 > 319) x0 = 319;
  int y1 = y0 + 1 < 240 ? y0 + 1 : 239;
  int x1 = x0 + 1 < 320 ? x0 + 1 : 319;
  double wy = sy - (double)y0;
  double wx = sx - (double)x0;
  const float* base = input + (size_t)b * 76800;
  double g00 = base[y0 * 320 + x0], g01 = base[y0 * 320 + x1];
  double g10 = base[y1 * 320 + x0], g11 = base[y1 * 320 + x1];
  double v = g00 * (1.0 - wy) * (1.0 - wx) + g01 * (1.0 - wy) * wx
           + g10 * wy * (1.0 - wx) + g11 * wy * wx;
  return (float)v;
}

// fused: per-block byte-format detect + mask scan + threefry filter into
// fixed per-(block,pick) uint32 slot segments. No global atomics.
// packed candidate: (m << 11) | (p & 2047), m < 2^17; sentinel 0xFFFFFFFF.
__global__ __launch_bounds__(256)
void k_cand(const void* __restrict__ mym, const void* __restrict__ msk,
            unsigned* __restrict__ done, uint32_t* __restrict__ cand) {
  __shared__ uint32_t s_cand[4][SLOTS];
  __shared__ unsigned s_cnt[4];
  __shared__ unsigned s_bytef;
  __shared__ unsigned s_kk[4][2];
  int b = blockIdx.x / CHUNKS;
  int chunk = blockIdx.x % CHUNKS;
  int tid = threadIdx.x;
  if (blockIdx.x == 0 && tid == 0) *done = 0;   // reset for k_loss (stream-ordered)
  if (tid < 4) {
    s_cnt[tid] = 0;
    uint32_t k0, k1; pick_key(b * 4 + tid, k0, k1);
    s_kk[tid][0] = k0; s_kk[tid][1] = k1;
  }
  if (tid == 4) s_bytef = 0;
  ((uint32_t*)s_cand)[tid] = 0xFFFFFFFFu;       // sentinel-fill all 256 slots
  long base = (long)b * NPIX;
  int start = chunk * CHUNK_PX;
  // detect on this block's msk window at BYTE offsets (in-bounds for both dtypes):
  // a word with all bytes in {0,1} and value>1 can only be byte-packed bools.
  {
    const unsigned* w = (const unsigned*)((const uint8_t*)msk + base + start);
    unsigned a0 = w[tid], a1 = w[tid + 256];
    unsigned f = ((a0 & 0xFEFEFEFEu) == 0u && a0 > 1u) ||
                 ((a1 & 0xFEFEFEFEu) == 0u && a1 > 1u);
    if (f) atomicOr(&s_bytef, 1u);
  }
  __syncthreads();
  unsigned bytef = s_bytef;
  uint32_t kk00 = s_kk[0][0], kk01 = s_kk[0][1];
  uint32_t kk10 = s_kk[1][0], kk11 = s_kk[1][1];
  uint32_t kk20 = s_kk[2][0], kk21 = s_kk[2][1];
  uint32_t kk30 = s_kk[3][0], kk31 = s_kk[3][1];

#define EMIT(my_, p) do {                                                       \
    int t0_ = (my_) ? 0 : 2;                                                    \
    uint32_t ka0_ = (my_) ? kk00 : kk20, ka1_ = (my_) ? kk01 : kk21;            \
    uint32_t kb0_ = (my_) ? kk10 : kk30, kb1_ = (my_) ? kk11 : kk31;            \
    uint32_t mA_ = rbits(ka0_, ka1_, (p)) >> 9;                                 \
    if (mA_ < T0) {                                                             \
      unsigned s_ = atomicAdd(&s_cnt[t0_], 1u);                                 \
      if (s_ < SLOTS) s_cand[t0_][s_] = (mA_ << 11) | ((unsigned)(p) & 2047u);  \
    }                                                                           \
    uint32_t mB_ = rbits(kb0_, kb1_, (p)) >> 9;                                 \
    if (mB_ < T0) {                                                             \
      unsigned s_ = atomicAdd(&s_cnt[t0_ + 1], 1u);                             \
      if (s_ < SLOTS) s_cand[t0_ + 1][s_] = (mB_ << 11) | ((unsigned)(p) & 2047u); \
    }                                                                           \
  } while (0)

  if (bytef) {
    const uint2* mkw = (const uint2*)((const uint8_t*)msk + base + start);
    const uint2* myw = (const uint2*)((const uint8_t*)mym + base + start);
    uint2 wk = mkw[tid];                        // 256 threads x 8 px = whole chunk
    uint2 wm = myw[tid];
    int p0 = start + tid * 8;
    #pragma unroll
    for (int s = 0; s < 4; ++s)
      if ((wk.x >> (8 * s)) & 0xFFu) EMIT(((wm.x >> (8 * s)) & 0xFFu) != 0u, p0 + s);
    #pragma unroll
    for (int s = 0; s < 4; ++s)
      if ((wk.y >> (8 * s)) & 0xFFu) EMIT(((wm.y >> (8 * s)) & 0xFFu) != 0u, p0 + 4 + s);
  } else {
    const int4* mk4 = (const int4*)((const int*)msk + base + start);
    const int4* my4 = (const int4*)((const int*)mym + base + start);
    for (int it = 0; it < 2; ++it) {
      int idx = it * 256 + tid;
      int4 k = mk4[idx];
      int4 m = my4[idx];
      int p0 = start + idx * 4;
      if (k.x) EMIT(m.x != 0, p0);
      if (k.y) EMIT(m.y != 0, p0 + 1);
      if (k.z) EMIT(m.z != 0, p0 + 2);
      if (k.w) EMIT(m.w != 0, p0 + 3);
    }
  }
#undef EMIT
  __syncthreads();
  // copy out fixed segment: thread t -> (pick t>>6, slot t&63), coalesced
  int pk = tid >> 6, sl = tid & 63;
  cand[((size_t)(b * 4 + pk) * CHUNKS + chunk) * SLOTS + sl] = s_cand[pk][sl];
}

// per pick: ONE global read (slots register-resident) -> bucket scatter (512
// bins) -> wave prefix scan -> exact rank via in-bin compares -> gather.
__global__ __launch_bounds__(1024)
void k_fsel(const float* __restrict__ input, const float* __restrict__ target,
            const uint32_t* __restrict__ cand, float* __restrict__ vals) {
  __shared__ uint32_t s_bkt[FBINS][BCAP];   // 48 KB
  __shared__ unsigned s_hcnt[FBINS];
  __shared__ unsigned s_cum[FBINS];         // exclusive cumsum
  __shared__ unsigned s_wsum[FBINS / 64];
  __shared__ unsigned s_T;
  int tid = threadIdx.x, pick = blockIdx.x;
  int b = pick >> 2, t = pick & 3;
  if (tid < FBINS) s_hcnt[tid] = 0;
  if (tid == 0) s_T = 0xFFFFu;
  const uint32_t* cp = cand + (size_t)pick * NSLOT;
  uint32_t wreg[10];                         // static indexing -> stays in VGPRs
  #pragma unroll
  for (int k = 0; k < 10; ++k) {
    int i = tid + k * 1024;
    wreg[k] = (i < NSLOT) ? cp[i] : 0xFFFFFFFFu;
  }
  __syncthreads();
  // pass 1: histogram + bucket scatter (w27 = (m&255)<<19 | p, unique 27-bit)
  #pragma unroll
  for (int k = 0; k < 10; ++k) {
    uint32_t w = wreg[k];
    if (w == 0xFFFFFFFFu) continue;
    unsigned m = w >> 11;
    unsigned bin = m >> 8;                       // m < 2^17 -> bin < 512
    unsigned p = ((unsigned)(tid + k * 1024) >> 6) * 2048u + (w & 2047u);
    unsigned w27 = ((m & 255u) << 19) | p;
    unsigned s = atomicAdd(&s_hcnt[bin], 1u);
    if (s < BCAP) s_bkt[bin][s] = w27;
  }
  __syncthreads();
  // wave-level inclusive scan over 512 bins (waves 0..7)
  unsigned incl = 0;
  if (tid < FBINS) {
    unsigned x = s_hcnt[tid];
    #pragma unroll
    for (int off = 1; off < 64; off <<= 1) {
      unsigned y = __shfl_up(x, off, 64);
      if ((tid & 63) >= off) x += y;
    }
    if ((tid & 63) == 63) s_wsum[tid >> 6] = x;
    incl = x;
  }
  __syncthreads();
  if (tid == 0) {
    unsigned run = 0;
    for (int wv = 0; wv < FBINS / 64; ++wv) {
      unsigned c = s_wsum[wv]; s_wsum[wv] = run; run += c;
    }
  }
  __syncthreads();
  if (tid < FBINS) {
    incl += s_wsum[tid >> 6];
    unsigned cnt = s_hcnt[tid];
    unsigned excl = incl - cnt;
    s_cum[tid] = excl;
    if (incl >= SN && excl < SN) s_T = (unsigned)tid;  // unique threshold bin
  }
  __syncthreads();
  unsigned T = s_T;
  // pass 2 (from registers): rank = excl_cum[bin] + #same-bin-smaller
  #pragma unroll
  for (int k = 0; k < 10; ++k) {
    uint32_t w = wreg[k];
    if (w == 0xFFFFFFFFu) continue;
    unsigned m = w >> 11;
    unsigned bin = m >> 8;
    if (bin > T) continue;
    unsigned p = ((unsigned)(tid + k * 1024) >> 6) * 2048u + (w & 2047u);
    unsigned w27 = ((m & 255u) << 19) | p;
    unsigned cnt = s_hcnt[bin]; if (cnt > BCAP) cnt = BCAP;
    unsigned local = 0;
    for (unsigned j = 0; j < cnt; ++j) local += (s_bkt[bin][j] < w27) ? 1u : 0u;
    unsigned r = s_cum[bin] + local;
    if (r < SN) {
      float v = (t & 1) ? target[(long)b * NPIX + (int)p]
                        : bilinear_val(input, b, (int)p);
      vals[(size_t)pick * SN + r] = v;
    }
  }
}

// pairwise loss partials + last-block final sum (deterministic: fixed read order)
__global__ __launch_bounds__(256)
void k_loss(const float* __restrict__ vals, float* __restrict__ partials,
            unsigned* __restrict__ done, float* __restrict__ out) {
  int bb = blockIdx.x / LCHUNKS;
  int ch = blockIdx.x % LCHUNKS;
  const float* ii = vals + (size_t)(4 * bb + 0) * SN;
  const float* it = vals + (size_t)(4 * bb + 1) * SN;
  const float* oi = vals + (size_t)(4 * bb + 2) * SN;
  const float* ot = vals + (size_t)(4 * bb + 3) * SN;
  __shared__ float s_oi[SN], s_ot[SN];
  __shared__ float s_ii[LROWS], s_it[LROWS];
  int tid = threadIdx.x;
  int a0 = ch * LROWS;
  for (int j = tid; j < SN; j += 256) { s_oi[j] = oi[j]; s_ot[j] = ot[j]; }
  if (tid < LROWS) s_ii[tid] = ii[a0 + tid];
  else if (tid >= 64 && tid < 64 + LROWS) s_it[tid - 64] = it[a0 + tid - 64];
  __syncthreads();
  float acc = 0.f;
  if (tid < 250) {
    float4 o4 = ((const float4*)s_oi)[tid];       // one-time LDS b128 reads;
    float4 t4 = ((const float4*)s_ot)[tid];       // inner loop is pure VALU
    #pragma unroll 8
    for (int a = 0; a < LROWS; ++a) {
      float iia = s_ii[a], ita = s_it[a];         // LDS broadcast (same addr)
      acc += fabsf(fabsf(iia - o4.x) - fabsf(ita - t4.x));
      acc += fabsf(fabsf(iia - o4.y) - fabsf(ita - t4.y));
      acc += fabsf(fabsf(iia - o4.z) - fabsf(ita - t4.z));
      acc += fabsf(fabsf(iia - o4.w) - fabsf(ita - t4.w));
    }
  }
  // wave shuffle reduction (4 waves) + 4-word LDS combine
  #pragma unroll
  for (int off = 32; off > 0; off >>= 1) acc += __shfl_down(acc, off, 64);
  __shared__ float s_w[4];
  __shared__ unsigned s_last;
  if ((tid & 63) == 0) s_w[tid >> 6] = acc;
  __syncthreads();
  if (tid == 0) {
    partials[blockIdx.x] = s_w[0] + s_w[1] + s_w[2] + s_w[3];
    __threadfence();                              // partial visible device-wide
    s_last = atomicAdd(done, 1u);
  }
  __syncthreads();
  if (s_last != (unsigned)(gridDim.x - 1)) return;
  // last block: device-scope atomic reads of all partials, fixed order
  if (tid < 64) {
    double acc2 = 0.0;
    for (int i = tid; i < NLOSS; i += 64)
      acc2 += (double)atomicAdd(&partials[i], 0.0f);
    #pragma unroll
    for (int off = 32; off > 0; off >>= 1)
      acc2 += __shfl_down(acc2, off, 64);
    if (tid == 0) out[0] = (float)(acc2 * 1e-6);
  }
}

extern "C" void kernel_launch(void* const* d_in, const int* in_sizes, int n_in,
                              void* d_out, int out_size, void* d_ws, size_t ws_size,
                              hipStream_t stream) {
  const float* input  = (const float*)d_in[0];
  const float* target = (const float*)d_in[1];
  const void* mym = d_in[2];
  const void* msk = d_in[3];
  (void)in_sizes; (void)n_in; (void)out_size; (void)ws_size;

  unsigned* ws_u32 = (unsigned*)d_ws;
  unsigned* done  = ws_u32 + WS_DONE / 4;
  uint32_t* cand  = (uint32_t*)((char*)d_ws + WS_CAND);
  float* vals     = (float*)((char*)d_ws + WS_VALS);
  float* partials = (float*)((char*)d_ws + WS_PART);

  k_cand<<<B_ * CHUNKS, 256, 0, stream>>>(mym, msk, done, cand);
  k_fsel<<<NPICK, 1024, 0, stream>>>(input, target, cand, vals);
  k_loss<<<NLOSS, 256, 0, stream>>>(vals, partials, done, (float*)d_out);
}